// Round 1
// baseline (1438.512 us; speedup 1.0000x reference)
//
#include <hip/hip_runtime.h>
#include <hip/hip_bf16.h>

#define NN 40000
#define NE 640000
#define NG 1000

__device__ __forceinline__ float gelu_t(float x) {
    float u = 0.7978845608028654f * (x + 0.044715f * x * x * x);
    return 0.5f * x * (1.0f + tanhf(u));
}
__device__ __forceinline__ unsigned f2ord(float f) {
    unsigned u = __float_as_uint(f);
    return (u & 0x80000000u) ? ~u : (u | 0x80000000u);
}
__device__ __forceinline__ float ord2f(unsigned u) {
    unsigned b = (u & 0x80000000u) ? (u ^ 0x80000000u) : ~u;
    return __uint_as_float(b);
}
__device__ __forceinline__ void atomAddF(float* p, float v) {
    unsafeAtomicAdd(p, v);
}

// ---------------- Kernel A: edge aggregation (agg_x, agg_ea, deg) ------------
// 16 threads per edge; each thread: one float4 of x + one ea scalar.
__global__ __launch_bounds__(256) void k_aggregate(
    const float* __restrict__ x, const float* __restrict__ eattr,
    const int* __restrict__ src, const int* __restrict__ dst,
    float* __restrict__ agg_x, float* __restrict__ agg_ea, float* __restrict__ deg) {
    int t = blockIdx.x * 256 + threadIdx.x;
    int e = t >> 4;
    int sub = t & 15;
    if (e >= NE) return;
    int s = src[e], d = dst[e];
    float4 xv = ((const float4*)x)[(size_t)s * 16 + sub];
    float* axd = agg_x + (size_t)d * 64 + sub * 4;
    atomAddF(axd + 0, xv.x); atomAddF(axd + 1, xv.y);
    atomAddF(axd + 2, xv.z); atomAddF(axd + 3, xv.w);
    atomAddF(agg_ea + (size_t)d * 16 + sub, eattr[(size_t)e * 16 + sub]);
    if (sub == 0) atomAddF(deg + d, 1.0f);
}

// ---------------- Kernel B: h = gelu(concatA @ concatW + biases) -------------
// A = [x | agg_x | agg_ea]  (N x 144), W = [W_self; W_msg; W_edge1] (144 x 256)
__global__ __launch_bounds__(256) void k_h(
    const float* __restrict__ x, const float* __restrict__ agg_x,
    const float* __restrict__ agg_ea, const float* __restrict__ deg,
    const float* __restrict__ W_self, const float* __restrict__ W_msg,
    const float* __restrict__ W_e1, const float* __restrict__ b_self,
    const float* __restrict__ b_msg, const float* __restrict__ b_e1,
    float* __restrict__ h) {
    __shared__ float As[16][64];
    __shared__ float Bs[16][64];
    int bx = blockIdx.x;   // col block 0..3
    int by = blockIdx.y;   // row block 0..624
    int t = threadIdx.x;
    int tx = t & 15, ty = t >> 4;
    int li = t >> 2;            // A-load row 0..63
    int lk4 = (t & 3) * 4;      // A-load k (float4)
    int lc = t & 63;            // B-load col
    int lkb = t >> 6;           // B-load k base 0..3
    float acc[4][4] = {};
    for (int kt = 0; kt < 9; ++kt) {
        const float* asrc; int stride; int kbase;
        if (kt < 4)      { asrc = x;      stride = 64; kbase = kt * 16; }
        else if (kt < 8) { asrc = agg_x;  stride = 64; kbase = (kt - 4) * 16; }
        else             { asrc = agg_ea; stride = 16; kbase = 0; }
        int n = by * 64 + li;
        float4 av = *(const float4*)(asrc + (size_t)n * stride + kbase + lk4);
        As[lk4 + 0][li] = av.x; As[lk4 + 1][li] = av.y;
        As[lk4 + 2][li] = av.z; As[lk4 + 3][li] = av.w;
        const float* bsrc;
        if (kt < 4)      bsrc = W_self + kt * 16 * 256;
        else if (kt < 8) bsrc = W_msg + (kt - 4) * 16 * 256;
        else             bsrc = W_e1;
        #pragma unroll
        for (int j = 0; j < 4; ++j) {
            int kk = lkb + j * 4;
            Bs[kk][lc] = bsrc[kk * 256 + bx * 64 + lc];
        }
        __syncthreads();
        #pragma unroll
        for (int k = 0; k < 16; ++k) {
            float4 a = *(const float4*)&As[k][ty * 4];
            float4 b = *(const float4*)&Bs[k][tx * 4];
            acc[0][0] += a.x * b.x; acc[0][1] += a.x * b.y; acc[0][2] += a.x * b.z; acc[0][3] += a.x * b.w;
            acc[1][0] += a.y * b.x; acc[1][1] += a.y * b.y; acc[1][2] += a.y * b.z; acc[1][3] += a.y * b.w;
            acc[2][0] += a.z * b.x; acc[2][1] += a.z * b.y; acc[2][2] += a.z * b.z; acc[2][3] += a.z * b.w;
            acc[3][0] += a.w * b.x; acc[3][1] += a.w * b.y; acc[3][2] += a.w * b.z; acc[3][3] += a.w * b.w;
        }
        __syncthreads();
    }
    int c0 = bx * 64 + tx * 4;
    #pragma unroll
    for (int r = 0; r < 4; ++r) {
        int n = by * 64 + ty * 4 + r;
        float dg = deg[n];
        float4 o;
        float* op = &o.x;
        #pragma unroll
        for (int cc = 0; cc < 4; ++cc) {
            int c = c0 + cc;
            op[cc] = gelu_t(acc[r][cc] + b_self[c] + dg * (b_msg[c] + b_e1[c]));
        }
        *(float4*)(h + (size_t)n * 256 + c0) = o;
    }
}

// ---------------- Kernel C: xl = h@W_l + b_l ; xr = h@W_r + b_r --------------
__global__ __launch_bounds__(256) void k_xlr(
    const float* __restrict__ h, const float* __restrict__ W_l,
    const float* __restrict__ W_r, const float* __restrict__ b_l,
    const float* __restrict__ b_r, float* __restrict__ xl, float* __restrict__ xr) {
    __shared__ float As[16][64];
    __shared__ float Bs[16][64];
    int bx = blockIdx.x;   // 0,1 -> xl ; 2,3 -> xr
    int by = blockIdx.y;
    int t = threadIdx.x;
    int tx = t & 15, ty = t >> 4;
    int li = t >> 2;
    int lk4 = (t & 3) * 4;
    int lc = t & 63;
    int lkb = t >> 6;
    const float* W = (bx < 2) ? W_l : W_r;
    const float* bias = (bx < 2) ? b_l : b_r;
    float* outp = (bx < 2) ? xl : xr;
    int cb = (bx & 1) * 64;
    float acc[4][4] = {};
    for (int kt = 0; kt < 16; ++kt) {
        int n = by * 64 + li;
        float4 av = *(const float4*)(h + (size_t)n * 256 + kt * 16 + lk4);
        As[lk4 + 0][li] = av.x; As[lk4 + 1][li] = av.y;
        As[lk4 + 2][li] = av.z; As[lk4 + 3][li] = av.w;
        #pragma unroll
        for (int j = 0; j < 4; ++j) {
            int kk = lkb + j * 4;
            Bs[kk][lc] = W[(size_t)(kt * 16 + kk) * 128 + cb + lc];
        }
        __syncthreads();
        #pragma unroll
        for (int k = 0; k < 16; ++k) {
            float4 a = *(const float4*)&As[k][ty * 4];
            float4 b = *(const float4*)&Bs[k][tx * 4];
            acc[0][0] += a.x * b.x; acc[0][1] += a.x * b.y; acc[0][2] += a.x * b.z; acc[0][3] += a.x * b.w;
            acc[1][0] += a.y * b.x; acc[1][1] += a.y * b.y; acc[1][2] += a.y * b.z; acc[1][3] += a.y * b.w;
            acc[2][0] += a.z * b.x; acc[2][1] += a.z * b.y; acc[2][2] += a.z * b.z; acc[2][3] += a.z * b.w;
            acc[3][0] += a.w * b.x; acc[3][1] += a.w * b.y; acc[3][2] += a.w * b.z; acc[3][3] += a.w * b.w;
        }
        __syncthreads();
    }
    int cl0 = cb + tx * 4;
    #pragma unroll
    for (int r = 0; r < 4; ++r) {
        int n = by * 64 + ty * 4 + r;
        float4 o;
        float* op = &o.x;
        #pragma unroll
        for (int cc = 0; cc < 4; ++cc) op[cc] = acc[r][cc] + bias[cl0 + cc];
        *(float4*)(outp + (size_t)n * 128 + cl0) = o;
    }
}

// ---------------- Kernel D: per-edge GATv2 scores + segment max --------------
// 1 wave handles 8 items (items = E real edges then N self-loops).
__global__ __launch_bounds__(256) void k_scores(
    const float* __restrict__ xl, const float* __restrict__ xr,
    const float* __restrict__ eattr, const int* __restrict__ src,
    const int* __restrict__ dst, const float* __restrict__ agg_ea,
    const float* __restrict__ deg, const float* __restrict__ W_e2,
    const float* __restrict__ att, float* __restrict__ alpha,
    unsigned* __restrict__ amax) {
    int t = threadIdx.x;
    int lane = t & 63;
    int wave = blockIdx.x * 4 + (t >> 6);
    int c0 = lane, c1 = lane + 64;
    float w0[16], w1[16];
    #pragma unroll
    for (int j = 0; j < 16; ++j) { w0[j] = W_e2[j * 128 + c0]; w1[j] = W_e2[j * 128 + c1]; }
    float a0 = att[c0], a1 = att[c1];
    int item0 = wave * 8;
    for (int ii = 0; ii < 8; ++ii) {
        int item = item0 + ii;
        if (item >= NE + NN) return;
        int s, d;
        float eav[16];
        if (item < NE) {
            s = src[item]; d = dst[item];
            const float4* ep = (const float4*)(eattr + (size_t)item * 16);
            float4 e0 = ep[0], e1 = ep[1], e2 = ep[2], e3 = ep[3];
            eav[0]=e0.x; eav[1]=e0.y; eav[2]=e0.z; eav[3]=e0.w;
            eav[4]=e1.x; eav[5]=e1.y; eav[6]=e1.z; eav[7]=e1.w;
            eav[8]=e2.x; eav[9]=e2.y; eav[10]=e2.z; eav[11]=e2.w;
            eav[12]=e3.x; eav[13]=e3.y; eav[14]=e3.z; eav[15]=e3.w;
        } else {
            int n = item - NE;
            s = n; d = n;
            float inv = 1.0f / fmaxf(deg[n], 1.0f);
            const float4* ep = (const float4*)(agg_ea + (size_t)n * 16);
            float4 e0 = ep[0], e1 = ep[1], e2 = ep[2], e3 = ep[3];
            eav[0]=e0.x*inv; eav[1]=e0.y*inv; eav[2]=e0.z*inv; eav[3]=e0.w*inv;
            eav[4]=e1.x*inv; eav[5]=e1.y*inv; eav[6]=e1.z*inv; eav[7]=e1.w*inv;
            eav[8]=e2.x*inv; eav[9]=e2.y*inv; eav[10]=e2.z*inv; eav[11]=e2.w*inv;
            eav[12]=e3.x*inv; eav[13]=e3.y*inv; eav[14]=e3.z*inv; eav[15]=e3.w*inv;
        }
        float m0 = xl[(size_t)s * 128 + c0] + xr[(size_t)d * 128 + c0];
        float m1 = xl[(size_t)s * 128 + c1] + xr[(size_t)d * 128 + c1];
        #pragma unroll
        for (int j = 0; j < 16; ++j) { m0 += eav[j] * w0[j]; m1 += eav[j] * w1[j]; }
        m0 = (m0 > 0.f) ? m0 : 0.2f * m0;
        m1 = (m1 > 0.f) ? m1 : 0.2f * m1;
        float part = m0 * a0 + m1 * a1;
        #pragma unroll
        for (int off = 32; off; off >>= 1) part += __shfl_xor(part, off, 64);
        if (lane == 0) {
            alpha[item] = part;
            atomicMax(&amax[d], f2ord(part));
        }
    }
}

// ---------------- Kernel E: weighted accumulation (num, denom) ---------------
__global__ __launch_bounds__(256) void k_accum(
    const float* __restrict__ xl, const int* __restrict__ src,
    const int* __restrict__ dst, const float* __restrict__ alpha,
    const unsigned* __restrict__ amax, float* __restrict__ num,
    float* __restrict__ denom) {
    int t = threadIdx.x;
    int item = blockIdx.x * 2 + (t >> 7);
    int c = t & 127;
    if (item >= NE + NN) return;
    int s, d;
    if (item < NE) { s = src[item]; d = dst[item]; }
    else { s = item - NE; d = s; }
    float w = __expf(alpha[item] - ord2f(amax[d]));
    atomAddF(&num[(size_t)d * 128 + c], w * xl[(size_t)s * 128 + c]);
    if (c == 0) atomAddF(&denom[d], w);
}

// ---------------- Kernel F: normalize + global mean pool ---------------------
__global__ __launch_bounds__(256) void k_pool(
    const float* __restrict__ num, const float* __restrict__ denom,
    const float* __restrict__ bias2, const int* __restrict__ batch,
    float* __restrict__ gsum, float* __restrict__ cnt) {
    int t = threadIdx.x;
    int n = blockIdx.x * 2 + (t >> 7);
    int c = t & 127;
    if (n >= NN) return;
    int g = batch[n];
    float v = num[(size_t)n * 128 + c] / denom[n] + bias2[c];
    atomAddF(&gsum[(size_t)g * 128 + c], v);
    if (c == 0) atomAddF(&cnt[g], 1.0f);
}

// ---------------- Kernel G: FFN --------------------------------------------
__global__ __launch_bounds__(256) void k_ffn(
    const float* __restrict__ gsum, const float* __restrict__ cnt,
    const float* __restrict__ W1, const float* __restrict__ b1,
    const float* __restrict__ W2, const float* __restrict__ b2,
    float* __restrict__ y) {
    __shared__ float row[128];
    __shared__ float red[4];
    int g = blockIdx.x;
    int t = threadIdx.x;
    if (t < 128) row[t] = gsum[(size_t)g * 128 + t] / fmaxf(cnt[g], 1.0f);
    __syncthreads();
    float part = 0.f;
    #pragma unroll
    for (int jj = 0; jj < 2; ++jj) {
        int j = t + jj * 256;
        float acc = b1[j];
        for (int k = 0; k < 128; ++k) acc += row[k] * W1[k * 512 + j];
        part += gelu_t(acc) * W2[j];
    }
    #pragma unroll
    for (int off = 32; off; off >>= 1) part += __shfl_xor(part, off, 64);
    if ((t & 63) == 0) red[t >> 6] = part;
    __syncthreads();
    if (t == 0) y[g] = red[0] + red[1] + red[2] + red[3] + b2[0];
}

extern "C" void kernel_launch(void* const* d_in, const int* in_sizes, int n_in,
                              void* d_out, int out_size, void* d_ws, size_t ws_size,
                              hipStream_t stream) {
    const float* x      = (const float*)d_in[0];
    const int*   eidx   = (const int*)d_in[1];
    const float* eattr  = (const float*)d_in[2];
    const int*   batch  = (const int*)d_in[3];
    const float* W_msg  = (const float*)d_in[4];
    const float* b_msg  = (const float*)d_in[5];
    const float* W_e1   = (const float*)d_in[6];
    const float* b_e1   = (const float*)d_in[7];
    const float* W_self = (const float*)d_in[8];
    const float* b_self = (const float*)d_in[9];
    const float* W_l    = (const float*)d_in[10];
    const float* b_l    = (const float*)d_in[11];
    const float* W_r    = (const float*)d_in[12];
    const float* b_r    = (const float*)d_in[13];
    const float* W_e2   = (const float*)d_in[14];
    const float* att    = (const float*)d_in[15];
    const float* bias2  = (const float*)d_in[16];
    const float* W1     = (const float*)d_in[17];
    const float* b1     = (const float*)d_in[18];
    const float* W2     = (const float*)d_in[19];
    const float* b2     = (const float*)d_in[20];
    const int* src = eidx;
    const int* dst = eidx + NE;

    float* ws = (float*)d_ws;
    size_t o = 0;
    float* agg_x  = ws + o; o += (size_t)NN * 64;
    float* agg_ea = ws + o; o += (size_t)NN * 16;
    float* deg    = ws + o; o += NN;
    float* denom  = ws + o; o += NN;
    float* num    = ws + o; o += (size_t)NN * 128;
    float* gsum   = ws + o; o += (size_t)NG * 128;
    float* cnt    = ws + o; o += 1024;
    unsigned* amax = (unsigned*)(ws + o); o += NN;
    size_t zero_bytes = o * sizeof(float);
    float* h     = ws + o; o += (size_t)NN * 256;
    float* xl    = ws + o; o += (size_t)NN * 128;
    float* xr    = ws + o; o += (size_t)NN * 128;
    float* alpha = ws + o; o += (size_t)(NE + NN);

    hipMemsetAsync(d_ws, 0, zero_bytes, stream);
    hipLaunchKernelGGL(k_aggregate, dim3(NE * 16 / 256), dim3(256), 0, stream,
                       x, eattr, src, dst, agg_x, agg_ea, deg);
    hipLaunchKernelGGL(k_h, dim3(4, 625), dim3(256), 0, stream,
                       x, agg_x, agg_ea, deg, W_self, W_msg, W_e1, b_self, b_msg, b_e1, h);
    hipLaunchKernelGGL(k_xlr, dim3(4, 625), dim3(256), 0, stream,
                       h, W_l, W_r, b_l, b_r, xl, xr);
    hipLaunchKernelGGL(k_scores, dim3((NE + NN) / (4 * 8)), dim3(256), 0, stream,
                       xl, xr, eattr, src, dst, agg_ea, deg, W_e2, att, alpha, amax);
    hipLaunchKernelGGL(k_accum, dim3((NE + NN) / 2), dim3(256), 0, stream,
                       xl, src, dst, alpha, amax, num, denom);
    hipLaunchKernelGGL(k_pool, dim3(NN / 2), dim3(256), 0, stream,
                       num, denom, bias2, batch, gsum, cnt);
    hipLaunchKernelGGL(k_ffn, dim3(NG), dim3(256), 0, stream,
                       gsum, cnt, W1, b1, W2, b2, (float*)d_out);
}

// Round 2
// 729.721 us; speedup vs baseline: 1.9713x; 1.9713x over previous
//
#include <hip/hip_runtime.h>
#include <hip/hip_bf16.h>

#define NN 40000
#define NE 640000
#define NG 1000

__device__ __forceinline__ float gelu_t(float x) {
    float u = 0.7978845608028654f * (x + 0.044715f * x * x * x);
    return 0.5f * x * (1.0f + tanhf(u));
}
__device__ __forceinline__ void atomAddF(float* p, float v) {
    unsafeAtomicAdd(p, v);
}

// ---------------- CSR build: histogram ---------------------------------------
__global__ __launch_bounds__(256) void k_hist(const int* __restrict__ dst,
                                              int* __restrict__ hist) {
    int e = blockIdx.x * 256 + threadIdx.x;
    if (e < NE) atomicAdd(&hist[dst[e]], 1);
}

// ---------------- CSR build: single-block exclusive scan ---------------------
__global__ __launch_bounds__(1024) void k_scan(const int* __restrict__ hist,
                                               int* __restrict__ row_ptr,
                                               int* __restrict__ cursor) {
    __shared__ int ssum[1024];
    int t = threadIdx.x;
    int base = t * 40;
    int local[40];
    int s = 0;
    #pragma unroll
    for (int j = 0; j < 40; ++j) {
        int idx = base + j;
        int v = (idx < NN) ? hist[idx] : 0;
        local[j] = s;
        s += v;
    }
    ssum[t] = s;
    __syncthreads();
    // Hillis-Steele inclusive scan over 1024 block sums
    for (int off = 1; off < 1024; off <<= 1) {
        int tmp = (t >= off) ? ssum[t - off] : 0;
        __syncthreads();
        ssum[t] += tmp;
        __syncthreads();
    }
    int prefix = (t > 0) ? ssum[t - 1] : 0;
    #pragma unroll
    for (int j = 0; j < 40; ++j) {
        int idx = base + j;
        if (idx < NN) {
            int v = prefix + local[j];
            row_ptr[idx] = v;
            cursor[idx] = v;
        }
    }
    if (t == 0) row_ptr[NN] = NE;
}

// ---------------- CSR build: scatter edge ids --------------------------------
__global__ __launch_bounds__(256) void k_scatter(const int* __restrict__ src,
                                                 const int* __restrict__ dst,
                                                 int* __restrict__ cursor,
                                                 int* __restrict__ csr_src,
                                                 int* __restrict__ csr_eid) {
    int e = blockIdx.x * 256 + threadIdx.x;
    if (e >= NE) return;
    int d = dst[e];
    int pos = atomicAdd(&cursor[d], 1);
    csr_src[pos] = src[e];
    csr_eid[pos] = e;
}

// ---------------- Kernel A': per-dst gather aggregation ----------------------
// one wave per dst node; lane = x column (64 cols). No atomics.
__global__ __launch_bounds__(256) void k_agg(
    const float* __restrict__ x, const float* __restrict__ eattr,
    const int* __restrict__ csr_src, const int* __restrict__ csr_eid,
    const int* __restrict__ row_ptr,
    float* __restrict__ agg_x, float* __restrict__ agg_ea) {
    int wave = blockIdx.x * 4 + (threadIdx.x >> 6);
    int lane = threadIdx.x & 63;
    if (wave >= NN) return;
    int d = wave;
    int beg = row_ptr[d], end = row_ptr[d + 1];
    float sx = 0.f, sea = 0.f;
    int elane = lane & 15;
    for (int i = beg; i < end; ++i) {
        int s = __builtin_amdgcn_readfirstlane(csr_src[i]);
        int e = __builtin_amdgcn_readfirstlane(csr_eid[i]);
        sx += x[(size_t)s * 64 + lane];
        sea += eattr[(size_t)e * 16 + elane];
    }
    agg_x[(size_t)d * 64 + lane] = sx;
    if (lane < 16) agg_ea[(size_t)d * 16 + lane] = sea;
}

// ---------------- Kernel B: h = gelu(concatA @ concatW + biases) -------------
// A = [x | agg_x | agg_ea]  (N x 144), W = [W_self; W_msg; W_edge1] (144 x 256)
__global__ __launch_bounds__(256) void k_h(
    const float* __restrict__ x, const float* __restrict__ agg_x,
    const float* __restrict__ agg_ea, const int* __restrict__ row_ptr,
    const float* __restrict__ W_self, const float* __restrict__ W_msg,
    const float* __restrict__ W_e1, const float* __restrict__ b_self,
    const float* __restrict__ b_msg, const float* __restrict__ b_e1,
    float* __restrict__ h) {
    __shared__ float As[16][64];
    __shared__ float Bs[16][64];
    int bx = blockIdx.x;   // col block 0..3
    int by = blockIdx.y;   // row block 0..624
    int t = threadIdx.x;
    int tx = t & 15, ty = t >> 4;
    int li = t >> 2;            // A-load row 0..63
    int lk4 = (t & 3) * 4;      // A-load k (float4)
    int lc = t & 63;            // B-load col
    int lkb = t >> 6;           // B-load k base 0..3
    float acc[4][4] = {};
    for (int kt = 0; kt < 9; ++kt) {
        const float* asrc; int stride; int kbase;
        if (kt < 4)      { asrc = x;      stride = 64; kbase = kt * 16; }
        else if (kt < 8) { asrc = agg_x;  stride = 64; kbase = (kt - 4) * 16; }
        else             { asrc = agg_ea; stride = 16; kbase = 0; }
        int n = by * 64 + li;
        float4 av = *(const float4*)(asrc + (size_t)n * stride + kbase + lk4);
        As[lk4 + 0][li] = av.x; As[lk4 + 1][li] = av.y;
        As[lk4 + 2][li] = av.z; As[lk4 + 3][li] = av.w;
        const float* bsrc;
        if (kt < 4)      bsrc = W_self + kt * 16 * 256;
        else if (kt < 8) bsrc = W_msg + (kt - 4) * 16 * 256;
        else             bsrc = W_e1;
        #pragma unroll
        for (int j = 0; j < 4; ++j) {
            int kk = lkb + j * 4;
            Bs[kk][lc] = bsrc[kk * 256 + bx * 64 + lc];
        }
        __syncthreads();
        #pragma unroll
        for (int k = 0; k < 16; ++k) {
            float4 a = *(const float4*)&As[k][ty * 4];
            float4 b = *(const float4*)&Bs[k][tx * 4];
            acc[0][0] += a.x * b.x; acc[0][1] += a.x * b.y; acc[0][2] += a.x * b.z; acc[0][3] += a.x * b.w;
            acc[1][0] += a.y * b.x; acc[1][1] += a.y * b.y; acc[1][2] += a.y * b.z; acc[1][3] += a.y * b.w;
            acc[2][0] += a.z * b.x; acc[2][1] += a.z * b.y; acc[2][2] += a.z * b.z; acc[2][3] += a.z * b.w;
            acc[3][0] += a.w * b.x; acc[3][1] += a.w * b.y; acc[3][2] += a.w * b.z; acc[3][3] += a.w * b.w;
        }
        __syncthreads();
    }
    int c0 = bx * 64 + tx * 4;
    #pragma unroll
    for (int r = 0; r < 4; ++r) {
        int n = by * 64 + ty * 4 + r;
        float dg = (float)(row_ptr[n + 1] - row_ptr[n]);
        float4 o;
        float* op = &o.x;
        #pragma unroll
        for (int cc = 0; cc < 4; ++cc) {
            int c = c0 + cc;
            op[cc] = gelu_t(acc[r][cc] + b_self[c] + dg * (b_msg[c] + b_e1[c]));
        }
        *(float4*)(h + (size_t)n * 256 + c0) = o;
    }
}

// ---------------- Kernel C: xl = h@W_l + b_l ; xr = h@W_r + b_r --------------
__global__ __launch_bounds__(256) void k_xlr(
    const float* __restrict__ h, const float* __restrict__ W_l,
    const float* __restrict__ W_r, const float* __restrict__ b_l,
    const float* __restrict__ b_r, float* __restrict__ xl, float* __restrict__ xr) {
    __shared__ float As[16][64];
    __shared__ float Bs[16][64];
    int bx = blockIdx.x;   // 0,1 -> xl ; 2,3 -> xr
    int by = blockIdx.y;
    int t = threadIdx.x;
    int tx = t & 15, ty = t >> 4;
    int li = t >> 2;
    int lk4 = (t & 3) * 4;
    int lc = t & 63;
    int lkb = t >> 6;
    const float* W = (bx < 2) ? W_l : W_r;
    const float* bias = (bx < 2) ? b_l : b_r;
    float* outp = (bx < 2) ? xl : xr;
    int cb = (bx & 1) * 64;
    float acc[4][4] = {};
    for (int kt = 0; kt < 16; ++kt) {
        int n = by * 64 + li;
        float4 av = *(const float4*)(h + (size_t)n * 256 + kt * 16 + lk4);
        As[lk4 + 0][li] = av.x; As[lk4 + 1][li] = av.y;
        As[lk4 + 2][li] = av.z; As[lk4 + 3][li] = av.w;
        #pragma unroll
        for (int j = 0; j < 4; ++j) {
            int kk = lkb + j * 4;
            Bs[kk][lc] = W[(size_t)(kt * 16 + kk) * 128 + cb + lc];
        }
        __syncthreads();
        #pragma unroll
        for (int k = 0; k < 16; ++k) {
            float4 a = *(const float4*)&As[k][ty * 4];
            float4 b = *(const float4*)&Bs[k][tx * 4];
            acc[0][0] += a.x * b.x; acc[0][1] += a.x * b.y; acc[0][2] += a.x * b.z; acc[0][3] += a.x * b.w;
            acc[1][0] += a.y * b.x; acc[1][1] += a.y * b.y; acc[1][2] += a.y * b.z; acc[1][3] += a.y * b.w;
            acc[2][0] += a.z * b.x; acc[2][1] += a.z * b.y; acc[2][2] += a.z * b.z; acc[2][3] += a.z * b.w;
            acc[3][0] += a.w * b.x; acc[3][1] += a.w * b.y; acc[3][2] += a.w * b.z; acc[3][3] += a.w * b.w;
        }
        __syncthreads();
    }
    int cl0 = cb + tx * 4;
    #pragma unroll
    for (int r = 0; r < 4; ++r) {
        int n = by * 64 + ty * 4 + r;
        float4 o;
        float* op = &o.x;
        #pragma unroll
        for (int cc = 0; cc < 4; ++cc) op[cc] = acc[r][cc] + bias[cl0 + cc];
        *(float4*)(outp + (size_t)n * 128 + cl0) = o;
    }
}

// ---------------- Kernel D': per-dst online-softmax GATv2 + pool -------------
// one wave per dst; lane handles cols c and c+64.
__global__ __launch_bounds__(256) void k_gat(
    const float* __restrict__ xl, const float* __restrict__ xr,
    const float* __restrict__ eattr, const int* __restrict__ csr_src,
    const int* __restrict__ csr_eid, const int* __restrict__ row_ptr,
    const float* __restrict__ agg_ea, const float* __restrict__ W_e2,
    const float* __restrict__ att, const float* __restrict__ bias2,
    const int* __restrict__ batch, float* __restrict__ gsum,
    float* __restrict__ cnt) {
    int wave = blockIdx.x * 4 + (threadIdx.x >> 6);
    int lane = threadIdx.x & 63;
    if (wave >= NN) return;
    int d = wave;
    int c0 = lane, c1 = lane + 64;
    float w0[16], w1[16];
    #pragma unroll
    for (int j = 0; j < 16; ++j) { w0[j] = W_e2[j * 128 + c0]; w1[j] = W_e2[j * 128 + c1]; }
    float a0 = att[c0], a1 = att[c1];
    float xr0 = xr[(size_t)d * 128 + c0], xr1 = xr[(size_t)d * 128 + c1];
    int beg = row_ptr[d], end = row_ptr[d + 1];
    float deg = (float)(end - beg);
    float m = -1e30f, l = 0.f, n0 = 0.f, n1 = 0.f;
    for (int i = beg; i <= end; ++i) {
        int s;
        float eav[16];
        if (i < end) {
            s = __builtin_amdgcn_readfirstlane(csr_src[i]);
            int e = __builtin_amdgcn_readfirstlane(csr_eid[i]);
            const float4* ep = (const float4*)(eattr + (size_t)e * 16);
            float4 e0 = ep[0], e1 = ep[1], e2 = ep[2], e3 = ep[3];
            eav[0]=e0.x; eav[1]=e0.y; eav[2]=e0.z; eav[3]=e0.w;
            eav[4]=e1.x; eav[5]=e1.y; eav[6]=e1.z; eav[7]=e1.w;
            eav[8]=e2.x; eav[9]=e2.y; eav[10]=e2.z; eav[11]=e2.w;
            eav[12]=e3.x; eav[13]=e3.y; eav[14]=e3.z; eav[15]=e3.w;
        } else {
            s = d;
            float inv = 1.0f / fmaxf(deg, 1.0f);
            const float4* ep = (const float4*)(agg_ea + (size_t)d * 16);
            float4 e0 = ep[0], e1 = ep[1], e2 = ep[2], e3 = ep[3];
            eav[0]=e0.x*inv; eav[1]=e0.y*inv; eav[2]=e0.z*inv; eav[3]=e0.w*inv;
            eav[4]=e1.x*inv; eav[5]=e1.y*inv; eav[6]=e1.z*inv; eav[7]=e1.w*inv;
            eav[8]=e2.x*inv; eav[9]=e2.y*inv; eav[10]=e2.z*inv; eav[11]=e2.w*inv;
            eav[12]=e3.x*inv; eav[13]=e3.y*inv; eav[14]=e3.z*inv; eav[15]=e3.w*inv;
        }
        float xl0 = xl[(size_t)s * 128 + c0];
        float xl1 = xl[(size_t)s * 128 + c1];
        float m0 = xl0 + xr0, m1 = xl1 + xr1;
        #pragma unroll
        for (int j = 0; j < 16; ++j) { m0 += eav[j] * w0[j]; m1 += eav[j] * w1[j]; }
        m0 = (m0 > 0.f) ? m0 : 0.2f * m0;
        m1 = (m1 > 0.f) ? m1 : 0.2f * m1;
        float part = m0 * a0 + m1 * a1;
        #pragma unroll
        for (int off = 32; off; off >>= 1) part += __shfl_xor(part, off, 64);
        float newm = fmaxf(m, part);
        float sc = __expf(m - newm);
        float w  = __expf(part - newm);
        l  = l * sc + w;
        n0 = n0 * sc + w * xl0;
        n1 = n1 * sc + w * xl1;
        m = newm;
    }
    float o0 = n0 / l + bias2[c0];
    float o1 = n1 / l + bias2[c1];
    int g = batch[d];
    atomAddF(&gsum[(size_t)g * 128 + c0], o0);
    atomAddF(&gsum[(size_t)g * 128 + c1], o1);
    if (lane == 0) atomAddF(&cnt[g], 1.0f);
}

// ---------------- Kernel G: FFN --------------------------------------------
__global__ __launch_bounds__(256) void k_ffn(
    const float* __restrict__ gsum, const float* __restrict__ cnt,
    const float* __restrict__ W1, const float* __restrict__ b1,
    const float* __restrict__ W2, const float* __restrict__ b2,
    float* __restrict__ y) {
    __shared__ float row[128];
    __shared__ float red[4];
    int g = blockIdx.x;
    int t = threadIdx.x;
    if (t < 128) row[t] = gsum[(size_t)g * 128 + t] / fmaxf(cnt[g], 1.0f);
    __syncthreads();
    float part = 0.f;
    #pragma unroll
    for (int jj = 0; jj < 2; ++jj) {
        int j = t + jj * 256;
        float acc = b1[j];
        for (int k = 0; k < 128; ++k) acc += row[k] * W1[k * 512 + j];
        part += gelu_t(acc) * W2[j];
    }
    #pragma unroll
    for (int off = 32; off; off >>= 1) part += __shfl_xor(part, off, 64);
    if ((t & 63) == 0) red[t >> 6] = part;
    __syncthreads();
    if (t == 0) y[g] = red[0] + red[1] + red[2] + red[3] + b2[0];
}

extern "C" void kernel_launch(void* const* d_in, const int* in_sizes, int n_in,
                              void* d_out, int out_size, void* d_ws, size_t ws_size,
                              hipStream_t stream) {
    const float* x      = (const float*)d_in[0];
    const int*   eidx   = (const int*)d_in[1];
    const float* eattr  = (const float*)d_in[2];
    const int*   batch  = (const int*)d_in[3];
    const float* W_msg  = (const float*)d_in[4];
    const float* b_msg  = (const float*)d_in[5];
    const float* W_e1   = (const float*)d_in[6];
    const float* b_e1   = (const float*)d_in[7];
    const float* W_self = (const float*)d_in[8];
    const float* b_self = (const float*)d_in[9];
    const float* W_l    = (const float*)d_in[10];
    const float* b_l    = (const float*)d_in[11];
    const float* W_r    = (const float*)d_in[12];
    const float* b_r    = (const float*)d_in[13];
    const float* W_e2   = (const float*)d_in[14];
    const float* att    = (const float*)d_in[15];
    const float* bias2  = (const float*)d_in[16];
    const float* W1     = (const float*)d_in[17];
    const float* b1     = (const float*)d_in[18];
    const float* W2     = (const float*)d_in[19];
    const float* b2     = (const float*)d_in[20];
    const int* src = eidx;
    const int* dst = eidx + NE;

    char* wsb = (char*)d_ws;
    size_t o = 0;
    // --- zero region: hist, gsum, cnt ---
    int*   hist   = (int*)(wsb + o);   o += (size_t)NN * 4;
    float* gsum   = (float*)(wsb + o); o += (size_t)NG * 128 * 4;
    float* cnt    = (float*)(wsb + o); o += 4096;
    size_t zero_bytes = o;
    // --- rest ---
    int*   row_ptr = (int*)(wsb + o);  o += (size_t)(NN + 1) * 4;
    int*   cursor  = (int*)(wsb + o);  o += (size_t)NN * 4;
    int*   csr_src = (int*)(wsb + o);  o += (size_t)NE * 4;
    int*   csr_eid = (int*)(wsb + o);  o += (size_t)NE * 4;
    float* agg_x   = (float*)(wsb + o); o += (size_t)NN * 64 * 4;
    float* agg_ea  = (float*)(wsb + o); o += (size_t)NN * 16 * 4;
    float* h       = (float*)(wsb + o); o += (size_t)NN * 256 * 4;
    float* xl      = (float*)(wsb + o); o += (size_t)NN * 128 * 4;
    float* xr      = (float*)(wsb + o); o += (size_t)NN * 128 * 4;

    hipMemsetAsync(d_ws, 0, zero_bytes, stream);
    hipLaunchKernelGGL(k_hist, dim3((NE + 255) / 256), dim3(256), 0, stream, dst, hist);
    hipLaunchKernelGGL(k_scan, dim3(1), dim3(1024), 0, stream, hist, row_ptr, cursor);
    hipLaunchKernelGGL(k_scatter, dim3((NE + 255) / 256), dim3(256), 0, stream,
                       src, dst, cursor, csr_src, csr_eid);
    hipLaunchKernelGGL(k_agg, dim3((NN + 3) / 4), dim3(256), 0, stream,
                       x, eattr, csr_src, csr_eid, row_ptr, agg_x, agg_ea);
    hipLaunchKernelGGL(k_h, dim3(4, 625), dim3(256), 0, stream,
                       x, agg_x, agg_ea, row_ptr, W_self, W_msg, W_e1, b_self, b_msg, b_e1, h);
    hipLaunchKernelGGL(k_xlr, dim3(4, 625), dim3(256), 0, stream,
                       h, W_l, W_r, b_l, b_r, xl, xr);
    hipLaunchKernelGGL(k_gat, dim3((NN + 3) / 4), dim3(256), 0, stream,
                       xl, xr, eattr, csr_src, csr_eid, row_ptr, agg_ea, W_e2, att, bias2,
                       batch, gsum, cnt);
    hipLaunchKernelGGL(k_ffn, dim3(NG), dim3(256), 0, stream,
                       gsum, cnt, W1, b1, W2, b2, (float*)d_out);
}

// Round 3
// 674.817 us; speedup vs baseline: 2.1317x; 1.0814x over previous
//
#include <hip/hip_runtime.h>
#include <hip/hip_bf16.h>

#define NN 40000
#define NE 640000
#define NG 1000

__device__ __forceinline__ float gelu_t(float x) {
    float u = 0.7978845608028654f * (x + 0.044715f * x * x * x);
    return 0.5f * x * (1.0f + tanhf(u));
}
__device__ __forceinline__ void atomAddF(float* p, float v) {
    unsafeAtomicAdd(p, v);
}
__device__ __forceinline__ int rfl(int v) { return __builtin_amdgcn_readfirstlane(v); }

// ---------------- CSR build: histogram ---------------------------------------
__global__ __launch_bounds__(256) void k_hist(const int* __restrict__ dst,
                                              int* __restrict__ hist) {
    int e = blockIdx.x * 256 + threadIdx.x;
    if (e < NE) atomicAdd(&hist[dst[e]], 1);
}

// ---------------- CSR build: single-block exclusive scan ---------------------
__global__ __launch_bounds__(1024) void k_scan(const int* __restrict__ hist,
                                               int* __restrict__ row_ptr,
                                               int* __restrict__ cursor) {
    __shared__ int ssum[1024];
    int t = threadIdx.x;
    int base = t * 40;
    int local[40];
    int s = 0;
    #pragma unroll
    for (int j = 0; j < 40; ++j) {
        int idx = base + j;
        int v = (idx < NN) ? hist[idx] : 0;
        local[j] = s;
        s += v;
    }
    ssum[t] = s;
    __syncthreads();
    for (int off = 1; off < 1024; off <<= 1) {
        int tmp = (t >= off) ? ssum[t - off] : 0;
        __syncthreads();
        ssum[t] += tmp;
        __syncthreads();
    }
    int prefix = (t > 0) ? ssum[t - 1] : 0;
    #pragma unroll
    for (int j = 0; j < 40; ++j) {
        int idx = base + j;
        if (idx < NN) {
            int v = prefix + local[j];
            row_ptr[idx] = v;
            cursor[idx] = v;
        }
    }
    if (t == 0) row_ptr[NN] = NE;
}

// ---------------- CSR build: scatter edge ids --------------------------------
__global__ __launch_bounds__(256) void k_scatter(const int* __restrict__ src,
                                                 const int* __restrict__ dst,
                                                 int* __restrict__ cursor,
                                                 int* __restrict__ csr_src,
                                                 int* __restrict__ csr_eid,
                                                 int* __restrict__ csr_dst) {
    int e = blockIdx.x * 256 + threadIdx.x;
    if (e >= NE) return;
    int d = dst[e];
    int pos = atomicAdd(&cursor[d], 1);
    csr_src[pos] = src[e];
    csr_eid[pos] = e;
    csr_dst[pos] = d;
}

// ---------------- Kernel A': per-dst gather aggregation (unroll 4) -----------
__global__ __launch_bounds__(256) void k_agg(
    const float* __restrict__ x, const float* __restrict__ eattr,
    const int* __restrict__ csr_src, const int* __restrict__ csr_eid,
    const int* __restrict__ row_ptr,
    float* __restrict__ agg_x, float* __restrict__ agg_ea) {
    int d = rfl(blockIdx.x * 4 + (threadIdx.x >> 6));
    int lane = threadIdx.x & 63;
    if (d >= NN) return;
    int beg = row_ptr[d], end = row_ptr[d + 1];
    int elane = lane & 15;
    float sx0 = 0.f, sx1 = 0.f, sx2 = 0.f, sx3 = 0.f;
    float se0 = 0.f, se1 = 0.f, se2 = 0.f, se3 = 0.f;
    int i = beg;
    for (; i + 3 < end; i += 4) {
        int s0 = rfl(csr_src[i]),     s1 = rfl(csr_src[i + 1]);
        int s2 = rfl(csr_src[i + 2]), s3 = rfl(csr_src[i + 3]);
        int e0 = rfl(csr_eid[i]),     e1 = rfl(csr_eid[i + 1]);
        int e2 = rfl(csr_eid[i + 2]), e3 = rfl(csr_eid[i + 3]);
        float a0 = x[(size_t)s0 * 64 + lane], a1 = x[(size_t)s1 * 64 + lane];
        float a2 = x[(size_t)s2 * 64 + lane], a3 = x[(size_t)s3 * 64 + lane];
        float b0 = eattr[(size_t)e0 * 16 + elane], b1 = eattr[(size_t)e1 * 16 + elane];
        float b2 = eattr[(size_t)e2 * 16 + elane], b3 = eattr[(size_t)e3 * 16 + elane];
        sx0 += a0; sx1 += a1; sx2 += a2; sx3 += a3;
        se0 += b0; se1 += b1; se2 += b2; se3 += b3;
    }
    for (; i < end; ++i) {
        int s = rfl(csr_src[i]);
        int e = rfl(csr_eid[i]);
        sx0 += x[(size_t)s * 64 + lane];
        se0 += eattr[(size_t)e * 16 + elane];
    }
    agg_x[(size_t)d * 64 + lane] = (sx0 + sx1) + (sx2 + sx3);
    if (lane < 16) agg_ea[(size_t)d * 16 + lane] = (se0 + se1) + (se2 + se3);
}

// ---------------- Kernel B: h = gelu(concatA @ concatW + biases) -------------
__global__ __launch_bounds__(256) void k_h(
    const float* __restrict__ x, const float* __restrict__ agg_x,
    const float* __restrict__ agg_ea, const int* __restrict__ row_ptr,
    const float* __restrict__ W_self, const float* __restrict__ W_msg,
    const float* __restrict__ W_e1, const float* __restrict__ b_self,
    const float* __restrict__ b_msg, const float* __restrict__ b_e1,
    float* __restrict__ h) {
    __shared__ float As[16][64];
    __shared__ float Bs[16][64];
    int bx = blockIdx.x;
    int by = blockIdx.y;
    int t = threadIdx.x;
    int tx = t & 15, ty = t >> 4;
    int li = t >> 2;
    int lk4 = (t & 3) * 4;
    int lc = t & 63;
    int lkb = t >> 6;
    float acc[4][4] = {};
    for (int kt = 0; kt < 9; ++kt) {
        const float* asrc; int stride; int kbase;
        if (kt < 4)      { asrc = x;      stride = 64; kbase = kt * 16; }
        else if (kt < 8) { asrc = agg_x;  stride = 64; kbase = (kt - 4) * 16; }
        else             { asrc = agg_ea; stride = 16; kbase = 0; }
        int n = by * 64 + li;
        float4 av = *(const float4*)(asrc + (size_t)n * stride + kbase + lk4);
        As[lk4 + 0][li] = av.x; As[lk4 + 1][li] = av.y;
        As[lk4 + 2][li] = av.z; As[lk4 + 3][li] = av.w;
        const float* bsrc;
        if (kt < 4)      bsrc = W_self + kt * 16 * 256;
        else if (kt < 8) bsrc = W_msg + (kt - 4) * 16 * 256;
        else             bsrc = W_e1;
        #pragma unroll
        for (int j = 0; j < 4; ++j) {
            int kk = lkb + j * 4;
            Bs[kk][lc] = bsrc[kk * 256 + bx * 64 + lc];
        }
        __syncthreads();
        #pragma unroll
        for (int k = 0; k < 16; ++k) {
            float4 a = *(const float4*)&As[k][ty * 4];
            float4 b = *(const float4*)&Bs[k][tx * 4];
            acc[0][0] += a.x * b.x; acc[0][1] += a.x * b.y; acc[0][2] += a.x * b.z; acc[0][3] += a.x * b.w;
            acc[1][0] += a.y * b.x; acc[1][1] += a.y * b.y; acc[1][2] += a.y * b.z; acc[1][3] += a.y * b.w;
            acc[2][0] += a.z * b.x; acc[2][1] += a.z * b.y; acc[2][2] += a.z * b.z; acc[2][3] += a.z * b.w;
            acc[3][0] += a.w * b.x; acc[3][1] += a.w * b.y; acc[3][2] += a.w * b.z; acc[3][3] += a.w * b.w;
        }
        __syncthreads();
    }
    int c0 = bx * 64 + tx * 4;
    #pragma unroll
    for (int r = 0; r < 4; ++r) {
        int n = by * 64 + ty * 4 + r;
        float dg = (float)(row_ptr[n + 1] - row_ptr[n]);
        float4 o;
        float* op = &o.x;
        #pragma unroll
        for (int cc = 0; cc < 4; ++cc) {
            int c = c0 + cc;
            op[cc] = gelu_t(acc[r][cc] + b_self[c] + dg * (b_msg[c] + b_e1[c]));
        }
        *(float4*)(h + (size_t)n * 256 + c0) = o;
    }
}

// ---------------- Kernel C: xl = h@W_l + b_l ; xr = h@W_r + b_r --------------
__global__ __launch_bounds__(256) void k_xlr(
    const float* __restrict__ h, const float* __restrict__ W_l,
    const float* __restrict__ W_r, const float* __restrict__ b_l,
    const float* __restrict__ b_r, float* __restrict__ xl, float* __restrict__ xr) {
    __shared__ float As[16][64];
    __shared__ float Bs[16][64];
    int bx = blockIdx.x;
    int by = blockIdx.y;
    int t = threadIdx.x;
    int tx = t & 15, ty = t >> 4;
    int li = t >> 2;
    int lk4 = (t & 3) * 4;
    int lc = t & 63;
    int lkb = t >> 6;
    const float* W = (bx < 2) ? W_l : W_r;
    const float* bias = (bx < 2) ? b_l : b_r;
    float* outp = (bx < 2) ? xl : xr;
    int cb = (bx & 1) * 64;
    float acc[4][4] = {};
    for (int kt = 0; kt < 16; ++kt) {
        int n = by * 64 + li;
        float4 av = *(const float4*)(h + (size_t)n * 256 + kt * 16 + lk4);
        As[lk4 + 0][li] = av.x; As[lk4 + 1][li] = av.y;
        As[lk4 + 2][li] = av.z; As[lk4 + 3][li] = av.w;
        #pragma unroll
        for (int j = 0; j < 4; ++j) {
            int kk = lkb + j * 4;
            Bs[kk][lc] = W[(size_t)(kt * 16 + kk) * 128 + cb + lc];
        }
        __syncthreads();
        #pragma unroll
        for (int k = 0; k < 16; ++k) {
            float4 a = *(const float4*)&As[k][ty * 4];
            float4 b = *(const float4*)&Bs[k][tx * 4];
            acc[0][0] += a.x * b.x; acc[0][1] += a.x * b.y; acc[0][2] += a.x * b.z; acc[0][3] += a.x * b.w;
            acc[1][0] += a.y * b.x; acc[1][1] += a.y * b.y; acc[1][2] += a.y * b.z; acc[1][3] += a.y * b.w;
            acc[2][0] += a.z * b.x; acc[2][1] += a.z * b.y; acc[2][2] += a.z * b.z; acc[2][3] += a.z * b.w;
            acc[3][0] += a.w * b.x; acc[3][1] += a.w * b.y; acc[3][2] += a.w * b.z; acc[3][3] += a.w * b.w;
        }
        __syncthreads();
    }
    int cl0 = cb + tx * 4;
    #pragma unroll
    for (int r = 0; r < 4; ++r) {
        int n = by * 64 + ty * 4 + r;
        float4 o;
        float* op = &o.x;
        #pragma unroll
        for (int cc = 0; cc < 4; ++cc) op[cc] = acc[r][cc] + bias[cl0 + cc];
        *(float4*)(outp + (size_t)n * 128 + cl0) = o;
    }
}

// ---------------- Kernel D1: edge-parallel GATv2 scores ----------------------
// items 0..NE-1 are CSR slots; items NE..NE+NN-1 are self-loops.
// one wave per 8 items; lane handles cols lane and lane+64.
__global__ __launch_bounds__(256) void k_score(
    const float* __restrict__ xl, const float* __restrict__ xr,
    const float* __restrict__ eattr, const int* __restrict__ csr_src,
    const int* __restrict__ csr_eid, const int* __restrict__ csr_dst,
    const int* __restrict__ row_ptr, const float* __restrict__ agg_ea,
    const float* __restrict__ W_e2, const float* __restrict__ att,
    float* __restrict__ alpha_csr, float* __restrict__ alpha_loop) {
    int t = threadIdx.x;
    int lane = t & 63;
    int wave = blockIdx.x * 4 + (t >> 6);
    int c0 = lane, c1 = lane + 64;
    float w0[16], w1[16];
    #pragma unroll
    for (int j = 0; j < 16; ++j) { w0[j] = W_e2[j * 128 + c0]; w1[j] = W_e2[j * 128 + c1]; }
    float a0 = att[c0], a1 = att[c1];
    int item0 = rfl(wave * 8);
    #pragma unroll 2
    for (int ii = 0; ii < 8; ++ii) {
        int item = item0 + ii;
        if (item >= NE + NN) return;
        int s, d;
        float eav[16];
        if (item < NE) {
            s = rfl(csr_src[item]); d = rfl(csr_dst[item]);
            int e = rfl(csr_eid[item]);
            const float4* ep = (const float4*)(eattr + (size_t)e * 16);
            float4 e0 = ep[0], e1 = ep[1], e2 = ep[2], e3 = ep[3];
            eav[0]=e0.x; eav[1]=e0.y; eav[2]=e0.z; eav[3]=e0.w;
            eav[4]=e1.x; eav[5]=e1.y; eav[6]=e1.z; eav[7]=e1.w;
            eav[8]=e2.x; eav[9]=e2.y; eav[10]=e2.z; eav[11]=e2.w;
            eav[12]=e3.x; eav[13]=e3.y; eav[14]=e3.z; eav[15]=e3.w;
        } else {
            int n = item - NE;
            s = n; d = n;
            float inv = 1.0f / fmaxf((float)(row_ptr[n + 1] - row_ptr[n]), 1.0f);
            const float4* ep = (const float4*)(agg_ea + (size_t)n * 16);
            float4 e0 = ep[0], e1 = ep[1], e2 = ep[2], e3 = ep[3];
            eav[0]=e0.x*inv; eav[1]=e0.y*inv; eav[2]=e0.z*inv; eav[3]=e0.w*inv;
            eav[4]=e1.x*inv; eav[5]=e1.y*inv; eav[6]=e1.z*inv; eav[7]=e1.w*inv;
            eav[8]=e2.x*inv; eav[9]=e2.y*inv; eav[10]=e2.z*inv; eav[11]=e2.w*inv;
            eav[12]=e3.x*inv; eav[13]=e3.y*inv; eav[14]=e3.z*inv; eav[15]=e3.w*inv;
        }
        float m0 = xl[(size_t)s * 128 + c0] + xr[(size_t)d * 128 + c0];
        float m1 = xl[(size_t)s * 128 + c1] + xr[(size_t)d * 128 + c1];
        #pragma unroll
        for (int j = 0; j < 16; ++j) { m0 += eav[j] * w0[j]; m1 += eav[j] * w1[j]; }
        m0 = (m0 > 0.f) ? m0 : 0.2f * m0;
        m1 = (m1 > 0.f) ? m1 : 0.2f * m1;
        float part = m0 * a0 + m1 * a1;
        #pragma unroll
        for (int off = 32; off; off >>= 1) part += __shfl_xor(part, off, 64);
        if (lane == 0) {
            if (item < NE) alpha_csr[item] = part;
            else           alpha_loop[item - NE] = part;
        }
    }
}

// ---------------- Kernel D2: per-dst softmax accumulate + pool ---------------
// one wave per dst; lane = cols c,c+64. Max precomputed lane-parallel; sums
// are non-recurrent (unrolled x4, independent gathers).
__global__ __launch_bounds__(256) void k_gat2(
    const float* __restrict__ xl, const int* __restrict__ csr_src,
    const int* __restrict__ row_ptr, const float* __restrict__ alpha_csr,
    const float* __restrict__ alpha_loop, const float* __restrict__ bias2,
    const int* __restrict__ batch, float* __restrict__ gsum,
    float* __restrict__ cnt) {
    int d = rfl(blockIdx.x * 4 + (threadIdx.x >> 6));
    int lane = threadIdx.x & 63;
    if (d >= NN) return;
    int c0 = lane, c1 = lane + 64;
    int beg = row_ptr[d], end = row_ptr[d + 1];
    // --- phase 1: max ---
    float mx = alpha_loop[d];
    for (int i = beg + lane; i < end; i += 64) mx = fmaxf(mx, alpha_csr[i]);
    #pragma unroll
    for (int off = 32; off; off >>= 1) mx = fmaxf(mx, __shfl_xor(mx, off, 64));
    // --- phase 2: sums (self-loop first) ---
    float wl = __expf(alpha_loop[d] - mx);
    float l = wl;
    float n0 = wl * xl[(size_t)d * 128 + c0];
    float n1 = wl * xl[(size_t)d * 128 + c1];
    float l1 = 0.f, n0b = 0.f, n1b = 0.f;
    int i = beg;
    for (; i + 3 < end; i += 4) {
        int s0 = rfl(csr_src[i]),     s1 = rfl(csr_src[i + 1]);
        int s2 = rfl(csr_src[i + 2]), s3 = rfl(csr_src[i + 3]);
        float w0 = __expf(alpha_csr[i]     - mx);
        float w1 = __expf(alpha_csr[i + 1] - mx);
        float w2 = __expf(alpha_csr[i + 2] - mx);
        float w3 = __expf(alpha_csr[i + 3] - mx);
        float p00 = xl[(size_t)s0 * 128 + c0], p01 = xl[(size_t)s0 * 128 + c1];
        float p10 = xl[(size_t)s1 * 128 + c0], p11 = xl[(size_t)s1 * 128 + c1];
        float p20 = xl[(size_t)s2 * 128 + c0], p21 = xl[(size_t)s2 * 128 + c1];
        float p30 = xl[(size_t)s3 * 128 + c0], p31 = xl[(size_t)s3 * 128 + c1];
        l  += w0 + w1; l1 += w2 + w3;
        n0  += w0 * p00 + w1 * p10;  n0b += w2 * p20 + w3 * p30;
        n1  += w0 * p01 + w1 * p11;  n1b += w2 * p21 + w3 * p31;
    }
    for (; i < end; ++i) {
        int s = rfl(csr_src[i]);
        float w = __expf(alpha_csr[i] - mx);
        l += w;
        n0 += w * xl[(size_t)s * 128 + c0];
        n1 += w * xl[(size_t)s * 128 + c1];
    }
    l += l1; n0 += n0b; n1 += n1b;
    float o0 = n0 / l + bias2[c0];
    float o1 = n1 / l + bias2[c1];
    int g = batch[d];
    atomAddF(&gsum[(size_t)g * 128 + c0], o0);
    atomAddF(&gsum[(size_t)g * 128 + c1], o1);
    if (lane == 0) atomAddF(&cnt[g], 1.0f);
}

// ---------------- Kernel G: FFN --------------------------------------------
__global__ __launch_bounds__(256) void k_ffn(
    const float* __restrict__ gsum, const float* __restrict__ cnt,
    const float* __restrict__ W1, const float* __restrict__ b1,
    const float* __restrict__ W2, const float* __restrict__ b2,
    float* __restrict__ y) {
    __shared__ float row[128];
    __shared__ float red[4];
    int g = blockIdx.x;
    int t = threadIdx.x;
    if (t < 128) row[t] = gsum[(size_t)g * 128 + t] / fmaxf(cnt[g], 1.0f);
    __syncthreads();
    float part = 0.f;
    #pragma unroll
    for (int jj = 0; jj < 2; ++jj) {
        int j = t + jj * 256;
        float acc = b1[j];
        for (int k = 0; k < 128; ++k) acc += row[k] * W1[k * 512 + j];
        part += gelu_t(acc) * W2[j];
    }
    #pragma unroll
    for (int off = 32; off; off >>= 1) part += __shfl_xor(part, off, 64);
    if ((t & 63) == 0) red[t >> 6] = part;
    __syncthreads();
    if (t == 0) y[g] = red[0] + red[1] + red[2] + red[3] + b2[0];
}

extern "C" void kernel_launch(void* const* d_in, const int* in_sizes, int n_in,
                              void* d_out, int out_size, void* d_ws, size_t ws_size,
                              hipStream_t stream) {
    const float* x      = (const float*)d_in[0];
    const int*   eidx   = (const int*)d_in[1];
    const float* eattr  = (const float*)d_in[2];
    const int*   batch  = (const int*)d_in[3];
    const float* W_msg  = (const float*)d_in[4];
    const float* b_msg  = (const float*)d_in[5];
    const float* W_e1   = (const float*)d_in[6];
    const float* b_e1   = (const float*)d_in[7];
    const float* W_self = (const float*)d_in[8];
    const float* b_self = (const float*)d_in[9];
    const float* W_l    = (const float*)d_in[10];
    const float* b_l    = (const float*)d_in[11];
    const float* W_r    = (const float*)d_in[12];
    const float* b_r    = (const float*)d_in[13];
    const float* W_e2   = (const float*)d_in[14];
    const float* att    = (const float*)d_in[15];
    const float* bias2  = (const float*)d_in[16];
    const float* W1     = (const float*)d_in[17];
    const float* b1     = (const float*)d_in[18];
    const float* W2     = (const float*)d_in[19];
    const float* b2     = (const float*)d_in[20];
    const int* src = eidx;
    const int* dst = eidx + NE;

    char* wsb = (char*)d_ws;
    size_t o = 0;
    // --- zero region: hist, gsum, cnt ---
    int*   hist   = (int*)(wsb + o);   o += (size_t)NN * 4;
    float* gsum   = (float*)(wsb + o); o += (size_t)NG * 128 * 4;
    float* cnt    = (float*)(wsb + o); o += 4096;
    size_t zero_bytes = o;
    // --- rest ---
    int*   row_ptr = (int*)(wsb + o);  o += (size_t)(NN + 1) * 4;
    int*   cursor  = (int*)(wsb + o);  o += (size_t)NN * 4;
    int*   csr_src = (int*)(wsb + o);  o += (size_t)NE * 4;
    int*   csr_eid = (int*)(wsb + o);  o += (size_t)NE * 4;
    int*   csr_dst = (int*)(wsb + o);  o += (size_t)NE * 4;
    float* alpha_csr  = (float*)(wsb + o); o += (size_t)NE * 4;
    float* alpha_loop = (float*)(wsb + o); o += (size_t)NN * 4;
    float* agg_x   = (float*)(wsb + o); o += (size_t)NN * 64 * 4;
    float* agg_ea  = (float*)(wsb + o); o += (size_t)NN * 16 * 4;
    float* h       = (float*)(wsb + o); o += (size_t)NN * 256 * 4;
    float* xl      = (float*)(wsb + o); o += (size_t)NN * 128 * 4;
    float* xr      = (float*)(wsb + o); o += (size_t)NN * 128 * 4;

    hipMemsetAsync(d_ws, 0, zero_bytes, stream);
    hipLaunchKernelGGL(k_hist, dim3((NE + 255) / 256), dim3(256), 0, stream, dst, hist);
    hipLaunchKernelGGL(k_scan, dim3(1), dim3(1024), 0, stream, hist, row_ptr, cursor);
    hipLaunchKernelGGL(k_scatter, dim3((NE + 255) / 256), dim3(256), 0, stream,
                       src, dst, cursor, csr_src, csr_eid, csr_dst);
    hipLaunchKernelGGL(k_agg, dim3((NN + 3) / 4), dim3(256), 0, stream,
                       x, eattr, csr_src, csr_eid, row_ptr, agg_x, agg_ea);
    hipLaunchKernelGGL(k_h, dim3(4, 625), dim3(256), 0, stream,
                       x, agg_x, agg_ea, row_ptr, W_self, W_msg, W_e1, b_self, b_msg, b_e1, h);
    hipLaunchKernelGGL(k_xlr, dim3(4, 625), dim3(256), 0, stream,
                       h, W_l, W_r, b_l, b_r, xl, xr);
    hipLaunchKernelGGL(k_score, dim3((NE + NN + 31) / 32), dim3(256), 0, stream,
                       xl, xr, eattr, csr_src, csr_eid, csr_dst, row_ptr, agg_ea,
                       W_e2, att, alpha_csr, alpha_loop);
    hipLaunchKernelGGL(k_gat2, dim3((NN + 3) / 4), dim3(256), 0, stream,
                       xl, csr_src, row_ptr, alpha_csr, alpha_loop, bias2,
                       batch, gsum, cnt);
    hipLaunchKernelGGL(k_ffn, dim3(NG), dim3(256), 0, stream,
                       gsum, cnt, W1, b1, W2, b2, (float*)d_out);
}

// Round 4
// 649.682 us; speedup vs baseline: 2.2142x; 1.0387x over previous
//
#include <hip/hip_runtime.h>
#include <hip/hip_bf16.h>

#define NN 40000
#define NE 640000
#define NG 1000

__device__ __forceinline__ float gelu_t(float x) {
    float u = 0.7978845608028654f * (x + 0.044715f * x * x * x);
    return 0.5f * x * (1.0f + tanhf(u));
}
__device__ __forceinline__ void atomAddF(float* p, float v) {
    unsafeAtomicAdd(p, v);
}
__device__ __forceinline__ int rfl(int v) { return __builtin_amdgcn_readfirstlane(v); }
__device__ __forceinline__ unsigned short f2bf(float f) {
    unsigned u = __float_as_uint(f);
    unsigned r = (u + 0x7fffu + ((u >> 16) & 1u)) >> 16;
    return (unsigned short)r;
}
__device__ __forceinline__ float bfl(unsigned p) { return __uint_as_float(p << 16); }
__device__ __forceinline__ float bfh(unsigned p) { return __uint_as_float(p & 0xffff0000u); }

// ---------------- CSR build: histogram ---------------------------------------
__global__ __launch_bounds__(256) void k_hist(const int* __restrict__ dst,
                                              int* __restrict__ hist) {
    int e = blockIdx.x * 256 + threadIdx.x;
    if (e < NE) atomicAdd(&hist[dst[e]], 1);
}

// ---------------- CSR build: single-block exclusive scan ---------------------
__global__ __launch_bounds__(1024) void k_scan(const int* __restrict__ hist,
                                               int* __restrict__ row_ptr,
                                               int* __restrict__ cursor) {
    __shared__ int ssum[1024];
    int t = threadIdx.x;
    int base = t * 40;
    int local[40];
    int s = 0;
    #pragma unroll
    for (int j = 0; j < 40; ++j) {
        int idx = base + j;
        int v = (idx < NN) ? hist[idx] : 0;
        local[j] = s;
        s += v;
    }
    ssum[t] = s;
    __syncthreads();
    for (int off = 1; off < 1024; off <<= 1) {
        int tmp = (t >= off) ? ssum[t - off] : 0;
        __syncthreads();
        ssum[t] += tmp;
        __syncthreads();
    }
    int prefix = (t > 0) ? ssum[t - 1] : 0;
    #pragma unroll
    for (int j = 0; j < 40; ++j) {
        int idx = base + j;
        if (idx < NN) {
            int v = prefix + local[j];
            row_ptr[idx] = v;
            cursor[idx] = v;
        }
    }
    if (t == 0) row_ptr[NN] = NE;
}

// ---------------- CSR build: scatter edge ids --------------------------------
__global__ __launch_bounds__(256) void k_scatter(const int* __restrict__ src,
                                                 const int* __restrict__ dst,
                                                 int* __restrict__ cursor,
                                                 int* __restrict__ csr_src,
                                                 int* __restrict__ csr_eid,
                                                 int* __restrict__ csr_dst) {
    int e = blockIdx.x * 256 + threadIdx.x;
    if (e >= NE) return;
    int d = dst[e];
    int pos = atomicAdd(&cursor[d], 1);
    csr_src[pos] = src[e];
    csr_eid[pos] = e;
    csr_dst[pos] = d;
}

// ---------------- x -> bf16 cast ---------------------------------------------
__global__ __launch_bounds__(256) void k_xbf(const float* __restrict__ x,
                                             unsigned short* __restrict__ x_bf) {
    int t = blockIdx.x * 256 + threadIdx.x;   // one float4 per thread
    if (t >= NN * 16) return;
    float4 v = ((const float4*)x)[t];
    unsigned p0 = (unsigned)f2bf(v.x) | ((unsigned)f2bf(v.y) << 16);
    unsigned p1 = (unsigned)f2bf(v.z) | ((unsigned)f2bf(v.w) << 16);
    ((uint2*)x_bf)[t] = make_uint2(p0, p1);
}

// ---------------- Kernel A': per-dst gather aggregation (bf16 x, unroll 4) ---
__global__ __launch_bounds__(256) void k_agg(
    const unsigned short* __restrict__ x_bf, const float* __restrict__ eattr,
    const int* __restrict__ csr_src, const int* __restrict__ csr_eid,
    const int* __restrict__ row_ptr,
    float* __restrict__ agg_x, float* __restrict__ agg_ea) {
    int d = rfl(blockIdx.x * 4 + (threadIdx.x >> 6));
    int lane = threadIdx.x & 63;
    if (d >= NN) return;
    int beg = row_ptr[d], end = row_ptr[d + 1];
    int elane = lane & 15;
    float sx0 = 0.f, sx1 = 0.f, sx2 = 0.f, sx3 = 0.f;
    float se0 = 0.f, se1 = 0.f, se2 = 0.f, se3 = 0.f;
    int i = beg;
    for (; i + 3 < end; i += 4) {
        int s0 = rfl(csr_src[i]),     s1 = rfl(csr_src[i + 1]);
        int s2 = rfl(csr_src[i + 2]), s3 = rfl(csr_src[i + 3]);
        int e0 = rfl(csr_eid[i]),     e1 = rfl(csr_eid[i + 1]);
        int e2 = rfl(csr_eid[i + 2]), e3 = rfl(csr_eid[i + 3]);
        float a0 = __uint_as_float((unsigned)x_bf[(size_t)s0 * 64 + lane] << 16);
        float a1 = __uint_as_float((unsigned)x_bf[(size_t)s1 * 64 + lane] << 16);
        float a2 = __uint_as_float((unsigned)x_bf[(size_t)s2 * 64 + lane] << 16);
        float a3 = __uint_as_float((unsigned)x_bf[(size_t)s3 * 64 + lane] << 16);
        float b0 = eattr[(size_t)e0 * 16 + elane], b1 = eattr[(size_t)e1 * 16 + elane];
        float b2 = eattr[(size_t)e2 * 16 + elane], b3 = eattr[(size_t)e3 * 16 + elane];
        sx0 += a0; sx1 += a1; sx2 += a2; sx3 += a3;
        se0 += b0; se1 += b1; se2 += b2; se3 += b3;
    }
    for (; i < end; ++i) {
        int s = rfl(csr_src[i]);
        int e = rfl(csr_eid[i]);
        sx0 += __uint_as_float((unsigned)x_bf[(size_t)s * 64 + lane] << 16);
        se0 += eattr[(size_t)e * 16 + elane];
    }
    agg_x[(size_t)d * 64 + lane] = (sx0 + sx1) + (sx2 + sx3);
    if (lane < 16) agg_ea[(size_t)d * 16 + lane] = (se0 + se1) + (se2 + se3);
}

// ---------------- Kernel B: h = gelu(concatA @ concatW + biases) -------------
__global__ __launch_bounds__(256) void k_h(
    const float* __restrict__ x, const float* __restrict__ agg_x,
    const float* __restrict__ agg_ea, const int* __restrict__ row_ptr,
    const float* __restrict__ W_self, const float* __restrict__ W_msg,
    const float* __restrict__ W_e1, const float* __restrict__ b_self,
    const float* __restrict__ b_msg, const float* __restrict__ b_e1,
    float* __restrict__ h) {
    __shared__ float As[16][64];
    __shared__ float Bs[16][64];
    int bx = blockIdx.x;
    int by = blockIdx.y;
    int t = threadIdx.x;
    int tx = t & 15, ty = t >> 4;
    int li = t >> 2;
    int lk4 = (t & 3) * 4;
    int lc = t & 63;
    int lkb = t >> 6;
    float acc[4][4] = {};
    for (int kt = 0; kt < 9; ++kt) {
        const float* asrc; int stride; int kbase;
        if (kt < 4)      { asrc = x;      stride = 64; kbase = kt * 16; }
        else if (kt < 8) { asrc = agg_x;  stride = 64; kbase = (kt - 4) * 16; }
        else             { asrc = agg_ea; stride = 16; kbase = 0; }
        int n = by * 64 + li;
        float4 av = *(const float4*)(asrc + (size_t)n * stride + kbase + lk4);
        As[lk4 + 0][li] = av.x; As[lk4 + 1][li] = av.y;
        As[lk4 + 2][li] = av.z; As[lk4 + 3][li] = av.w;
        const float* bsrc;
        if (kt < 4)      bsrc = W_self + kt * 16 * 256;
        else if (kt < 8) bsrc = W_msg + (kt - 4) * 16 * 256;
        else             bsrc = W_e1;
        #pragma unroll
        for (int j = 0; j < 4; ++j) {
            int kk = lkb + j * 4;
            Bs[kk][lc] = bsrc[kk * 256 + bx * 64 + lc];
        }
        __syncthreads();
        #pragma unroll
        for (int k = 0; k < 16; ++k) {
            float4 a = *(const float4*)&As[k][ty * 4];
            float4 b = *(const float4*)&Bs[k][tx * 4];
            acc[0][0] += a.x * b.x; acc[0][1] += a.x * b.y; acc[0][2] += a.x * b.z; acc[0][3] += a.x * b.w;
            acc[1][0] += a.y * b.x; acc[1][1] += a.y * b.y; acc[1][2] += a.y * b.z; acc[1][3] += a.y * b.w;
            acc[2][0] += a.z * b.x; acc[2][1] += a.z * b.y; acc[2][2] += a.z * b.z; acc[2][3] += a.z * b.w;
            acc[3][0] += a.w * b.x; acc[3][1] += a.w * b.y; acc[3][2] += a.w * b.z; acc[3][3] += a.w * b.w;
        }
        __syncthreads();
    }
    int c0 = bx * 64 + tx * 4;
    #pragma unroll
    for (int r = 0; r < 4; ++r) {
        int n = by * 64 + ty * 4 + r;
        float dg = (float)(row_ptr[n + 1] - row_ptr[n]);
        float4 o;
        float* op = &o.x;
        #pragma unroll
        for (int cc = 0; cc < 4; ++cc) {
            int c = c0 + cc;
            op[cc] = gelu_t(acc[r][cc] + b_self[c] + dg * (b_msg[c] + b_e1[c]));
        }
        *(float4*)(h + (size_t)n * 256 + c0) = o;
    }
}

// ---------------- Kernel C: xl/xr = h@W + b, written as packed bf16 ----------
__global__ __launch_bounds__(256) void k_xlr(
    const float* __restrict__ h, const float* __restrict__ W_l,
    const float* __restrict__ W_r, const float* __restrict__ b_l,
    const float* __restrict__ b_r, unsigned short* __restrict__ xl_bf,
    unsigned short* __restrict__ xr_bf) {
    __shared__ float As[16][64];
    __shared__ float Bs[16][64];
    int bx = blockIdx.x;
    int by = blockIdx.y;
    int t = threadIdx.x;
    int tx = t & 15, ty = t >> 4;
    int li = t >> 2;
    int lk4 = (t & 3) * 4;
    int lc = t & 63;
    int lkb = t >> 6;
    const float* W = (bx < 2) ? W_l : W_r;
    const float* bias = (bx < 2) ? b_l : b_r;
    unsigned short* outp = (bx < 2) ? xl_bf : xr_bf;
    int cb = (bx & 1) * 64;
    float acc[4][4] = {};
    for (int kt = 0; kt < 16; ++kt) {
        int n = by * 64 + li;
        float4 av = *(const float4*)(h + (size_t)n * 256 + kt * 16 + lk4);
        As[lk4 + 0][li] = av.x; As[lk4 + 1][li] = av.y;
        As[lk4 + 2][li] = av.z; As[lk4 + 3][li] = av.w;
        #pragma unroll
        for (int j = 0; j < 4; ++j) {
            int kk = lkb + j * 4;
            Bs[kk][lc] = W[(size_t)(kt * 16 + kk) * 128 + cb + lc];
        }
        __syncthreads();
        #pragma unroll
        for (int k = 0; k < 16; ++k) {
            float4 a = *(const float4*)&As[k][ty * 4];
            float4 b = *(const float4*)&Bs[k][tx * 4];
            acc[0][0] += a.x * b.x; acc[0][1] += a.x * b.y; acc[0][2] += a.x * b.z; acc[0][3] += a.x * b.w;
            acc[1][0] += a.y * b.x; acc[1][1] += a.y * b.y; acc[1][2] += a.y * b.z; acc[1][3] += a.y * b.w;
            acc[2][0] += a.z * b.x; acc[2][1] += a.z * b.y; acc[2][2] += a.z * b.z; acc[2][3] += a.z * b.w;
            acc[3][0] += a.w * b.x; acc[3][1] += a.w * b.y; acc[3][2] += a.w * b.z; acc[3][3] += a.w * b.w;
        }
        __syncthreads();
    }
    int cl0 = cb + tx * 4;
    #pragma unroll
    for (int r = 0; r < 4; ++r) {
        int n = by * 64 + ty * 4 + r;
        float v0 = acc[r][0] + bias[cl0 + 0];
        float v1 = acc[r][1] + bias[cl0 + 1];
        float v2 = acc[r][2] + bias[cl0 + 2];
        float v3 = acc[r][3] + bias[cl0 + 3];
        unsigned p0 = (unsigned)f2bf(v0) | ((unsigned)f2bf(v1) << 16);
        unsigned p1 = (unsigned)f2bf(v2) | ((unsigned)f2bf(v3) << 16);
        ((uint2*)outp)[(size_t)n * 32 + (cl0 >> 2)] = make_uint2(p0, p1);
    }
}

// ---------------- Kernel D1: edge-parallel GATv2 scores (bf16 rows) ----------
// lane covers cols (2*lane, 2*lane+1); one wave per 8 CSR slots.
__global__ __launch_bounds__(256) void k_score(
    const unsigned short* __restrict__ xl_bf, const unsigned short* __restrict__ xr_bf,
    const float* __restrict__ eattr, const int* __restrict__ csr_src,
    const int* __restrict__ csr_eid, const int* __restrict__ csr_dst,
    const float* __restrict__ W_e2, const float* __restrict__ att,
    float* __restrict__ alpha_csr) {
    int t = threadIdx.x;
    int lane = t & 63;
    int wave = blockIdx.x * 4 + (t >> 6);
    float w0[16], w1[16];
    #pragma unroll
    for (int j = 0; j < 16; ++j) {
        float2 wv = *(const float2*)(W_e2 + j * 128 + 2 * lane);
        w0[j] = wv.x; w1[j] = wv.y;
    }
    float2 av = *(const float2*)(att + 2 * lane);
    float a0 = av.x, a1 = av.y;
    const unsigned* xlw = (const unsigned*)xl_bf;
    const unsigned* xrw = (const unsigned*)xr_bf;
    int item0 = rfl(wave * 8);
    #pragma unroll 2
    for (int ii = 0; ii < 8; ++ii) {
        int item = item0 + ii;
        if (item >= NE) return;
        int s = rfl(csr_src[item]);
        int d = rfl(csr_dst[item]);
        int e = rfl(csr_eid[item]);
        const float4* ep = (const float4*)(eattr + (size_t)e * 16);
        float4 e0 = ep[0], e1 = ep[1], e2 = ep[2], e3 = ep[3];
        float eav[16] = {e0.x, e0.y, e0.z, e0.w, e1.x, e1.y, e1.z, e1.w,
                         e2.x, e2.y, e2.z, e2.w, e3.x, e3.y, e3.z, e3.w};
        unsigned pl = xlw[(size_t)s * 64 + lane];
        unsigned pr = xrw[(size_t)d * 64 + lane];
        float m0 = bfl(pl) + bfl(pr);
        float m1 = bfh(pl) + bfh(pr);
        #pragma unroll
        for (int j = 0; j < 16; ++j) { m0 += eav[j] * w0[j]; m1 += eav[j] * w1[j]; }
        m0 = (m0 > 0.f) ? m0 : 0.2f * m0;
        m1 = (m1 > 0.f) ? m1 : 0.2f * m1;
        float part = m0 * a0 + m1 * a1;
        #pragma unroll
        for (int off = 32; off; off >>= 1) part += __shfl_xor(part, off, 64);
        if (lane == 0) alpha_csr[item] = part;
    }
}

// ---------------- Kernel D1b: self-loop scores -------------------------------
__global__ __launch_bounds__(256) void k_score_loop(
    const unsigned short* __restrict__ xl_bf, const unsigned short* __restrict__ xr_bf,
    const int* __restrict__ row_ptr, const float* __restrict__ agg_ea,
    const float* __restrict__ W_e2, const float* __restrict__ att,
    float* __restrict__ alpha_loop) {
    int t = threadIdx.x;
    int lane = t & 63;
    int wave = blockIdx.x * 4 + (t >> 6);
    float w0[16], w1[16];
    #pragma unroll
    for (int j = 0; j < 16; ++j) {
        float2 wv = *(const float2*)(W_e2 + j * 128 + 2 * lane);
        w0[j] = wv.x; w1[j] = wv.y;
    }
    float2 av = *(const float2*)(att + 2 * lane);
    float a0 = av.x, a1 = av.y;
    const unsigned* xlw = (const unsigned*)xl_bf;
    const unsigned* xrw = (const unsigned*)xr_bf;
    int item0 = rfl(wave * 8);
    for (int ii = 0; ii < 8; ++ii) {
        int n = item0 + ii;
        if (n >= NN) return;
        float inv = 1.0f / fmaxf((float)(row_ptr[n + 1] - row_ptr[n]), 1.0f);
        const float4* ep = (const float4*)(agg_ea + (size_t)n * 16);
        float4 e0 = ep[0], e1 = ep[1], e2 = ep[2], e3 = ep[3];
        float eav[16] = {e0.x, e0.y, e0.z, e0.w, e1.x, e1.y, e1.z, e1.w,
                         e2.x, e2.y, e2.z, e2.w, e3.x, e3.y, e3.z, e3.w};
        unsigned pl = xlw[(size_t)n * 64 + lane];
        unsigned pr = xrw[(size_t)n * 64 + lane];
        float m0 = bfl(pl) + bfl(pr);
        float m1 = bfh(pl) + bfh(pr);
        #pragma unroll
        for (int j = 0; j < 16; ++j) { m0 += inv * eav[j] * w0[j]; m1 += inv * eav[j] * w1[j]; }
        m0 = (m0 > 0.f) ? m0 : 0.2f * m0;
        m1 = (m1 > 0.f) ? m1 : 0.2f * m1;
        float part = m0 * a0 + m1 * a1;
        #pragma unroll
        for (int off = 32; off; off >>= 1) part += __shfl_xor(part, off, 64);
        if (lane == 0) alpha_loop[n] = part;
    }
}

// ---------------- Kernel D2: per-dst softmax accumulate + pool ---------------
__global__ __launch_bounds__(256) void k_gat2(
    const unsigned short* __restrict__ xl_bf, const int* __restrict__ csr_src,
    const int* __restrict__ row_ptr, const float* __restrict__ alpha_csr,
    const float* __restrict__ alpha_loop, const float* __restrict__ bias2,
    const int* __restrict__ batch, float* __restrict__ gsum,
    float* __restrict__ cnt) {
    int d = rfl(blockIdx.x * 4 + (threadIdx.x >> 6));
    int lane = threadIdx.x & 63;
    if (d >= NN) return;
    const unsigned* xlw = (const unsigned*)xl_bf;
    int beg = row_ptr[d], end = row_ptr[d + 1];
    // --- phase 1: max ---
    float mx = alpha_loop[d];
    for (int i = beg + lane; i < end; i += 64) mx = fmaxf(mx, alpha_csr[i]);
    #pragma unroll
    for (int off = 32; off; off >>= 1) mx = fmaxf(mx, __shfl_xor(mx, off, 64));
    // --- phase 2: sums (self-loop first) ---
    float wl = __expf(alpha_loop[d] - mx);
    float l = wl;
    unsigned pd = xlw[(size_t)d * 64 + lane];
    float n0 = wl * bfl(pd);
    float n1 = wl * bfh(pd);
    float l1 = 0.f, n0b = 0.f, n1b = 0.f;
    int i = beg;
    for (; i + 3 < end; i += 4) {
        int s0 = rfl(csr_src[i]),     s1 = rfl(csr_src[i + 1]);
        int s2 = rfl(csr_src[i + 2]), s3 = rfl(csr_src[i + 3]);
        float w0 = __expf(alpha_csr[i]     - mx);
        float w1 = __expf(alpha_csr[i + 1] - mx);
        float w2 = __expf(alpha_csr[i + 2] - mx);
        float w3 = __expf(alpha_csr[i + 3] - mx);
        unsigned p0 = xlw[(size_t)s0 * 64 + lane];
        unsigned p1 = xlw[(size_t)s1 * 64 + lane];
        unsigned p2 = xlw[(size_t)s2 * 64 + lane];
        unsigned p3 = xlw[(size_t)s3 * 64 + lane];
        l  += w0 + w1; l1 += w2 + w3;
        n0  += w0 * bfl(p0) + w1 * bfl(p1);  n0b += w2 * bfl(p2) + w3 * bfl(p3);
        n1  += w0 * bfh(p0) + w1 * bfh(p1);  n1b += w2 * bfh(p2) + w3 * bfh(p3);
    }
    for (; i < end; ++i) {
        int s = rfl(csr_src[i]);
        float w = __expf(alpha_csr[i] - mx);
        unsigned p = xlw[(size_t)s * 64 + lane];
        l += w;
        n0 += w * bfl(p);
        n1 += w * bfh(p);
    }
    l += l1; n0 += n0b; n1 += n1b;
    float2 bv = *(const float2*)(bias2 + 2 * lane);
    float o0 = n0 / l + bv.x;
    float o1 = n1 / l + bv.y;
    int g = batch[d];
    atomAddF(&gsum[(size_t)g * 128 + 2 * lane], o0);
    atomAddF(&gsum[(size_t)g * 128 + 2 * lane + 1], o1);
    if (lane == 0) atomAddF(&cnt[g], 1.0f);
}

// ---------------- Kernel G: FFN --------------------------------------------
__global__ __launch_bounds__(256) void k_ffn(
    const float* __restrict__ gsum, const float* __restrict__ cnt,
    const float* __restrict__ W1, const float* __restrict__ b1,
    const float* __restrict__ W2, const float* __restrict__ b2,
    float* __restrict__ y) {
    __shared__ float row[128];
    __shared__ float red[4];
    int g = blockIdx.x;
    int t = threadIdx.x;
    if (t < 128) row[t] = gsum[(size_t)g * 128 + t] / fmaxf(cnt[g], 1.0f);
    __syncthreads();
    float part = 0.f;
    #pragma unroll
    for (int jj = 0; jj < 2; ++jj) {
        int j = t + jj * 256;
        float acc = b1[j];
        for (int k = 0; k < 128; ++k) acc += row[k] * W1[k * 512 + j];
        part += gelu_t(acc) * W2[j];
    }
    #pragma unroll
    for (int off = 32; off; off >>= 1) part += __shfl_xor(part, off, 64);
    if ((t & 63) == 0) red[t >> 6] = part;
    __syncthreads();
    if (t == 0) y[g] = red[0] + red[1] + red[2] + red[3] + b2[0];
}

extern "C" void kernel_launch(void* const* d_in, const int* in_sizes, int n_in,
                              void* d_out, int out_size, void* d_ws, size_t ws_size,
                              hipStream_t stream) {
    const float* x      = (const float*)d_in[0];
    const int*   eidx   = (const int*)d_in[1];
    const float* eattr  = (const float*)d_in[2];
    const int*   batch  = (const int*)d_in[3];
    const float* W_msg  = (const float*)d_in[4];
    const float* b_msg  = (const float*)d_in[5];
    const float* W_e1   = (const float*)d_in[6];
    const float* b_e1   = (const float*)d_in[7];
    const float* W_self = (const float*)d_in[8];
    const float* b_self = (const float*)d_in[9];
    const float* W_l    = (const float*)d_in[10];
    const float* b_l    = (const float*)d_in[11];
    const float* W_r    = (const float*)d_in[12];
    const float* b_r    = (const float*)d_in[13];
    const float* W_e2   = (const float*)d_in[14];
    const float* att    = (const float*)d_in[15];
    const float* bias2  = (const float*)d_in[16];
    const float* W1     = (const float*)d_in[17];
    const float* b1     = (const float*)d_in[18];
    const float* W2     = (const float*)d_in[19];
    const float* b2     = (const float*)d_in[20];
    const int* src = eidx;
    const int* dst = eidx + NE;

    char* wsb = (char*)d_ws;
    size_t o = 0;
    // --- zero region: hist, gsum, cnt ---
    int*   hist   = (int*)(wsb + o);   o += (size_t)NN * 4;
    float* gsum   = (float*)(wsb + o); o += (size_t)NG * 128 * 4;
    float* cnt    = (float*)(wsb + o); o += 4096;
    size_t zero_bytes = o;
    // --- rest ---
    int*   row_ptr = (int*)(wsb + o);  o += (size_t)(NN + 1) * 4;
    int*   cursor  = (int*)(wsb + o);  o += (size_t)NN * 4;
    int*   csr_src = (int*)(wsb + o);  o += (size_t)NE * 4;
    int*   csr_eid = (int*)(wsb + o);  o += (size_t)NE * 4;
    int*   csr_dst = (int*)(wsb + o);  o += (size_t)NE * 4;
    float* alpha_csr  = (float*)(wsb + o); o += (size_t)NE * 4;
    float* alpha_loop = (float*)(wsb + o); o += (size_t)NN * 4;
    float* agg_x   = (float*)(wsb + o); o += (size_t)NN * 64 * 4;
    float* agg_ea  = (float*)(wsb + o); o += (size_t)NN * 16 * 4;
    float* h       = (float*)(wsb + o); o += (size_t)NN * 256 * 4;
    unsigned short* x_bf  = (unsigned short*)(wsb + o); o += (size_t)NN * 64 * 2;
    unsigned short* xl_bf = (unsigned short*)(wsb + o); o += (size_t)NN * 128 * 2;
    unsigned short* xr_bf = (unsigned short*)(wsb + o); o += (size_t)NN * 128 * 2;

    hipMemsetAsync(d_ws, 0, zero_bytes, stream);
    hipLaunchKernelGGL(k_xbf, dim3(NN * 16 / 256), dim3(256), 0, stream, x, x_bf);
    hipLaunchKernelGGL(k_hist, dim3((NE + 255) / 256), dim3(256), 0, stream, dst, hist);
    hipLaunchKernelGGL(k_scan, dim3(1), dim3(1024), 0, stream, hist, row_ptr, cursor);
    hipLaunchKernelGGL(k_scatter, dim3((NE + 255) / 256), dim3(256), 0, stream,
                       src, dst, cursor, csr_src, csr_eid, csr_dst);
    hipLaunchKernelGGL(k_agg, dim3((NN + 3) / 4), dim3(256), 0, stream,
                       x_bf, eattr, csr_src, csr_eid, row_ptr, agg_x, agg_ea);
    hipLaunchKernelGGL(k_h, dim3(4, 625), dim3(256), 0, stream,
                       x, agg_x, agg_ea, row_ptr, W_self, W_msg, W_e1, b_self, b_msg, b_e1, h);
    hipLaunchKernelGGL(k_xlr, dim3(4, 625), dim3(256), 0, stream,
                       h, W_l, W_r, b_l, b_r, xl_bf, xr_bf);
    hipLaunchKernelGGL(k_score, dim3(NE / 32, 1), dim3(256), 0, stream,
                       xl_bf, xr_bf, eattr, csr_src, csr_eid, csr_dst, W_e2, att, alpha_csr);
    hipLaunchKernelGGL(k_score_loop, dim3((NN + 31) / 32), dim3(256), 0, stream,
                       xl_bf, xr_bf, row_ptr, agg_ea, W_e2, att, alpha_loop);
    hipLaunchKernelGGL(k_gat2, dim3((NN + 3) / 4), dim3(256), 0, stream,
                       xl_bf, csr_src, row_ptr, alpha_csr, alpha_loop, bias2,
                       batch, gsum, cnt);
    hipLaunchKernelGGL(k_ffn, dim3(NG), dim3(256), 0, stream,
                       gsum, cnt, W1, b1, W2, b2, (float*)d_out);
}

// Round 5
// 541.529 us; speedup vs baseline: 2.6564x; 1.1997x over previous
//
#include <hip/hip_runtime.h>
#include <hip/hip_bf16.h>

#define NN 40000
#define NE 640000
#define NG 1000

typedef __attribute__((ext_vector_type(8))) short short8;
typedef __attribute__((ext_vector_type(4))) float f32x4;

__device__ __forceinline__ float gelu_t(float x) {
    float u = 0.7978845608028654f * (x + 0.044715f * x * x * x);
    return 0.5f * x * (1.0f + tanhf(u));
}
__device__ __forceinline__ void atomAddF(float* p, float v) {
    unsafeAtomicAdd(p, v);
}
__device__ __forceinline__ int rfl(int v) { return __builtin_amdgcn_readfirstlane(v); }
__device__ __forceinline__ unsigned short f2bf(float f) {
    unsigned u = __float_as_uint(f);
    unsigned r = (u + 0x7fffu + ((u >> 16) & 1u)) >> 16;
    return (unsigned short)r;
}
__device__ __forceinline__ float bfl(unsigned p) { return __uint_as_float(p << 16); }
__device__ __forceinline__ float bfh(unsigned p) { return __uint_as_float(p & 0xffff0000u); }

// ---------------- CSR build: histogram ---------------------------------------
__global__ __launch_bounds__(256) void k_hist(const int* __restrict__ dst,
                                              int* __restrict__ hist) {
    int e = blockIdx.x * 256 + threadIdx.x;
    if (e < NE) atomicAdd(&hist[dst[e]], 1);
}

// ---------------- CSR build: single-block exclusive scan ---------------------
__global__ __launch_bounds__(1024) void k_scan(const int* __restrict__ hist,
                                               int* __restrict__ row_ptr,
                                               int* __restrict__ cursor) {
    __shared__ int ssum[1024];
    int t = threadIdx.x;
    int base = t * 40;
    int local[40];
    int s = 0;
    #pragma unroll
    for (int j = 0; j < 40; ++j) {
        int idx = base + j;
        int v = (idx < NN) ? hist[idx] : 0;
        local[j] = s;
        s += v;
    }
    ssum[t] = s;
    __syncthreads();
    for (int off = 1; off < 1024; off <<= 1) {
        int tmp = (t >= off) ? ssum[t - off] : 0;
        __syncthreads();
        ssum[t] += tmp;
        __syncthreads();
    }
    int prefix = (t > 0) ? ssum[t - 1] : 0;
    #pragma unroll
    for (int j = 0; j < 40; ++j) {
        int idx = base + j;
        if (idx < NN) {
            int v = prefix + local[j];
            row_ptr[idx] = v;
            cursor[idx] = v;
        }
    }
    if (t == 0) row_ptr[NN] = NE;
}

// ---------------- CSR build: scatter edge ids --------------------------------
__global__ __launch_bounds__(256) void k_scatter(const int* __restrict__ src,
                                                 const int* __restrict__ dst,
                                                 int* __restrict__ cursor,
                                                 int* __restrict__ csr_src,
                                                 int* __restrict__ csr_eid) {
    int e = blockIdx.x * 256 + threadIdx.x;
    if (e >= NE) return;
    int d = dst[e];
    int pos = atomicAdd(&cursor[d], 1);
    csr_src[pos] = src[e];
    csr_eid[pos] = e;
}

// ---------------- x -> bf16 cast ---------------------------------------------
__global__ __launch_bounds__(256) void k_xbf(const float* __restrict__ x,
                                             unsigned short* __restrict__ x_bf) {
    int t = blockIdx.x * 256 + threadIdx.x;   // one float4 per thread
    if (t >= NN * 16) return;
    float4 v = ((const float4*)x)[t];
    unsigned p0 = (unsigned)f2bf(v.x) | ((unsigned)f2bf(v.y) << 16);
    unsigned p1 = (unsigned)f2bf(v.z) | ((unsigned)f2bf(v.w) << 16);
    ((uint2*)x_bf)[t] = make_uint2(p0, p1);
}

// ---------------- W_l|W_r -> MFMA B-fragment repack --------------------------
// Wcat[k][n] (k=0..255 over H, n=0..255: 0-127=W_l cols, 128-255=W_r cols)
// frag slot: wfrag16[(nt*8+kt)*64 + lane] holds bf16x8 = Wcat[kt*32+(l>>4)*8+j][nt*16+(l&15)]
__global__ __launch_bounds__(256) void k_wrep(const float* __restrict__ W_l,
                                              const float* __restrict__ W_r,
                                              unsigned short* __restrict__ wfrag) {
    int t = blockIdx.x * 256 + threadIdx.x;   // 16*8*64 = 8192
    if (t >= 8192) return;
    int l = t & 63;
    int kt = (t >> 6) & 7;
    int nt = t >> 9;
    int n = nt * 16 + (l & 15);
    int k0 = kt * 32 + (l >> 4) * 8;
    const float* W = (n < 128) ? W_l : W_r;
    int nn = n & 127;
    unsigned short v[8];
    #pragma unroll
    for (int j = 0; j < 8; ++j) v[j] = f2bf(W[(size_t)(k0 + j) * 128 + nn]);
    uint4 pack;
    pack.x = (unsigned)v[0] | ((unsigned)v[1] << 16);
    pack.y = (unsigned)v[2] | ((unsigned)v[3] << 16);
    pack.z = (unsigned)v[4] | ((unsigned)v[5] << 16);
    pack.w = (unsigned)v[6] | ((unsigned)v[7] << 16);
    ((uint4*)wfrag)[t] = pack;
}

// ---------------- Kernel A': per-dst gather aggregation (bf16 x, unroll 4) ---
__global__ __launch_bounds__(256) void k_agg(
    const unsigned short* __restrict__ x_bf, const float* __restrict__ eattr,
    const int* __restrict__ csr_src, const int* __restrict__ csr_eid,
    const int* __restrict__ row_ptr,
    float* __restrict__ agg_x, float* __restrict__ agg_ea) {
    int d = rfl(blockIdx.x * 4 + (threadIdx.x >> 6));
    int lane = threadIdx.x & 63;
    if (d >= NN) return;
    int beg = row_ptr[d], end = row_ptr[d + 1];
    int elane = lane & 15;
    float sx0 = 0.f, sx1 = 0.f, sx2 = 0.f, sx3 = 0.f;
    float se0 = 0.f, se1 = 0.f, se2 = 0.f, se3 = 0.f;
    int i = beg;
    for (; i + 3 < end; i += 4) {
        int s0 = rfl(csr_src[i]),     s1 = rfl(csr_src[i + 1]);
        int s2 = rfl(csr_src[i + 2]), s3 = rfl(csr_src[i + 3]);
        int e0 = rfl(csr_eid[i]),     e1 = rfl(csr_eid[i + 1]);
        int e2 = rfl(csr_eid[i + 2]), e3 = rfl(csr_eid[i + 3]);
        float a0 = __uint_as_float((unsigned)x_bf[(size_t)s0 * 64 + lane] << 16);
        float a1 = __uint_as_float((unsigned)x_bf[(size_t)s1 * 64 + lane] << 16);
        float a2 = __uint_as_float((unsigned)x_bf[(size_t)s2 * 64 + lane] << 16);
        float a3 = __uint_as_float((unsigned)x_bf[(size_t)s3 * 64 + lane] << 16);
        float b0 = eattr[(size_t)e0 * 16 + elane], b1 = eattr[(size_t)e1 * 16 + elane];
        float b2 = eattr[(size_t)e2 * 16 + elane], b3 = eattr[(size_t)e3 * 16 + elane];
        sx0 += a0; sx1 += a1; sx2 += a2; sx3 += a3;
        se0 += b0; se1 += b1; se2 += b2; se3 += b3;
    }
    for (; i < end; ++i) {
        int s = rfl(csr_src[i]);
        int e = rfl(csr_eid[i]);
        sx0 += __uint_as_float((unsigned)x_bf[(size_t)s * 64 + lane] << 16);
        se0 += eattr[(size_t)e * 16 + elane];
    }
    agg_x[(size_t)d * 64 + lane] = (sx0 + sx1) + (sx2 + sx3);
    if (lane < 16) agg_ea[(size_t)d * 16 + lane] = (se0 + se1) + (se2 + se3);
}

// ---------------- Kernel B: h = gelu(concatA @ concatW + biases), bf16 out ---
__global__ __launch_bounds__(256) void k_h(
    const float* __restrict__ x, const float* __restrict__ agg_x,
    const float* __restrict__ agg_ea, const int* __restrict__ row_ptr,
    const float* __restrict__ W_self, const float* __restrict__ W_msg,
    const float* __restrict__ W_e1, const float* __restrict__ b_self,
    const float* __restrict__ b_msg, const float* __restrict__ b_e1,
    unsigned short* __restrict__ h_bf) {
    __shared__ float As[16][64];
    __shared__ float Bs[16][64];
    int bx = blockIdx.x;
    int by = blockIdx.y;
    int t = threadIdx.x;
    int tx = t & 15, ty = t >> 4;
    int li = t >> 2;
    int lk4 = (t & 3) * 4;
    int lc = t & 63;
    int lkb = t >> 6;
    float acc[4][4] = {};
    for (int kt = 0; kt < 9; ++kt) {
        const float* asrc; int stride; int kbase;
        if (kt < 4)      { asrc = x;      stride = 64; kbase = kt * 16; }
        else if (kt < 8) { asrc = agg_x;  stride = 64; kbase = (kt - 4) * 16; }
        else             { asrc = agg_ea; stride = 16; kbase = 0; }
        int n = by * 64 + li;
        float4 av = *(const float4*)(asrc + (size_t)n * stride + kbase + lk4);
        As[lk4 + 0][li] = av.x; As[lk4 + 1][li] = av.y;
        As[lk4 + 2][li] = av.z; As[lk4 + 3][li] = av.w;
        const float* bsrc;
        if (kt < 4)      bsrc = W_self + kt * 16 * 256;
        else if (kt < 8) bsrc = W_msg + (kt - 4) * 16 * 256;
        else             bsrc = W_e1;
        #pragma unroll
        for (int j = 0; j < 4; ++j) {
            int kk = lkb + j * 4;
            Bs[kk][lc] = bsrc[kk * 256 + bx * 64 + lc];
        }
        __syncthreads();
        #pragma unroll
        for (int k = 0; k < 16; ++k) {
            float4 a = *(const float4*)&As[k][ty * 4];
            float4 b = *(const float4*)&Bs[k][tx * 4];
            acc[0][0] += a.x * b.x; acc[0][1] += a.x * b.y; acc[0][2] += a.x * b.z; acc[0][3] += a.x * b.w;
            acc[1][0] += a.y * b.x; acc[1][1] += a.y * b.y; acc[1][2] += a.y * b.z; acc[1][3] += a.y * b.w;
            acc[2][0] += a.z * b.x; acc[2][1] += a.z * b.y; acc[2][2] += a.z * b.z; acc[2][3] += a.z * b.w;
            acc[3][0] += a.w * b.x; acc[3][1] += a.w * b.y; acc[3][2] += a.w * b.z; acc[3][3] += a.w * b.w;
        }
        __syncthreads();
    }
    int c0 = bx * 64 + tx * 4;
    #pragma unroll
    for (int r = 0; r < 4; ++r) {
        int n = by * 64 + ty * 4 + r;
        float dg = (float)(row_ptr[n + 1] - row_ptr[n]);
        float v[4];
        #pragma unroll
        for (int cc = 0; cc < 4; ++cc) {
            int c = c0 + cc;
            v[cc] = gelu_t(acc[r][cc] + b_self[c] + dg * (b_msg[c] + b_e1[c]));
        }
        unsigned q0 = (unsigned)f2bf(v[0]) | ((unsigned)f2bf(v[1]) << 16);
        unsigned q1 = (unsigned)f2bf(v[2]) | ((unsigned)f2bf(v[3]) << 16);
        ((uint2*)h_bf)[(size_t)n * 64 + (c0 >> 2)] = make_uint2(q0, q1);
    }
}

// ---------------- Kernel C: xl/xr via bf16 MFMA ------------------------------
// block = 64 rows x 256 cols; wave w covers cols [w*64, w*64+64).
__global__ __launch_bounds__(256) void k_xlr_mfma(
    const unsigned short* __restrict__ h_bf, const unsigned short* __restrict__ wfrag,
    const float* __restrict__ b_l, const float* __restrict__ b_r,
    unsigned short* __restrict__ xl_bf, unsigned short* __restrict__ xr_bf) {
    int w = threadIdx.x >> 6;
    int l = threadIdx.x & 63;
    int m0 = blockIdx.x * 64;
    int quad = l >> 4, lm = l & 15;
    f32x4 acc[4][4] = {};   // [mt][nt]
    for (int kt = 0; kt < 8; ++kt) {
        short8 a[4], b[4];
        #pragma unroll
        for (int mt = 0; mt < 4; ++mt) {
            int row = m0 + mt * 16 + lm;
            a[mt] = *(const short8*)(h_bf + (size_t)row * 256 + kt * 32 + quad * 8);
        }
        #pragma unroll
        for (int nt = 0; nt < 4; ++nt) {
            int gnt = w * 4 + nt;
            b[nt] = *(const short8*)(wfrag + (((size_t)(gnt * 8 + kt) * 64 + l) * 8));
        }
        #pragma unroll
        for (int mt = 0; mt < 4; ++mt)
            #pragma unroll
            for (int nt = 0; nt < 4; ++nt)
                acc[mt][nt] = __builtin_amdgcn_mfma_f32_16x16x32_bf16(a[mt], b[nt], acc[mt][nt], 0, 0, 0);
    }
    bool isl = (w < 2);
    unsigned short* outp = isl ? xl_bf : xr_bf;
    int colbase = isl ? w * 64 : (w - 2) * 64;
    const float* bias = isl ? b_l : b_r;
    #pragma unroll
    for (int nt = 0; nt < 4; ++nt) {
        int col = colbase + nt * 16 + lm;
        float bv = bias[col];
        #pragma unroll
        for (int mt = 0; mt < 4; ++mt) {
            #pragma unroll
            for (int r = 0; r < 4; ++r) {
                int row = m0 + mt * 16 + quad * 4 + r;
                outp[(size_t)row * 128 + col] = f2bf(acc[mt][nt][r] + bv);
            }
        }
    }
}

// ---------------- edge score helper ------------------------------------------
__device__ __forceinline__ float edge_score(const float4* __restrict__ ep, float scale,
                                            unsigned pl, float xr0, float xr1,
                                            const float* w0, const float* w1,
                                            float a0, float a1) {
    float4 e0 = ep[0], e1 = ep[1], e2 = ep[2], e3 = ep[3];
    float eav[16] = {e0.x, e0.y, e0.z, e0.w, e1.x, e1.y, e1.z, e1.w,
                     e2.x, e2.y, e2.z, e2.w, e3.x, e3.y, e3.z, e3.w};
    float m0 = bfl(pl) + xr0, m1 = bfh(pl) + xr1;
    #pragma unroll
    for (int j = 0; j < 16; ++j) {
        float ev = scale * eav[j];
        m0 += ev * w0[j]; m1 += ev * w1[j];
    }
    m0 = (m0 > 0.f) ? m0 : 0.2f * m0;
    m1 = (m1 > 0.f) ? m1 : 0.2f * m1;
    float part = m0 * a0 + m1 * a1;
    #pragma unroll
    for (int off = 32; off; off >>= 1) part += __shfl_xor(part, off, 64);
    return part;
}

__device__ __forceinline__ void online_upd(float al, unsigned p, float& m_run,
                                           float& l_run, float& n0, float& n1) {
    if (al > m_run) {   // rare; al is wave-uniform -> cheap branch
        float sc = __expf(m_run - al);
        l_run *= sc; n0 *= sc; n1 *= sc;
        m_run = al;
    }
    float wgt = __expf(al - m_run);
    l_run += wgt;
    n0 += wgt * bfl(p);
    n1 += wgt * bfh(p);
}

// ---------------- Kernel D: fused per-dst GATv2 (score+softmax+accum+pool) ---
__global__ __launch_bounds__(256) void k_gat(
    const unsigned* __restrict__ xlw, const unsigned* __restrict__ xrw,
    const float* __restrict__ eattr, const int* __restrict__ csr_src,
    const int* __restrict__ csr_eid, const int* __restrict__ row_ptr,
    const float* __restrict__ agg_ea, const float* __restrict__ W_e2,
    const float* __restrict__ att, const float* __restrict__ bias2,
    const int* __restrict__ batch, float* __restrict__ gsum,
    float* __restrict__ cnt) {
    int d = rfl(blockIdx.x * 4 + (threadIdx.x >> 6));
    int lane = threadIdx.x & 63;
    if (d >= NN) return;
    float w0[16], w1[16];
    #pragma unroll
    for (int j = 0; j < 16; ++j) {
        float2 wv = *(const float2*)(W_e2 + j * 128 + 2 * lane);
        w0[j] = wv.x; w1[j] = wv.y;
    }
    float2 av = *(const float2*)(att + 2 * lane);
    float a0 = av.x, a1 = av.y;
    int beg = row_ptr[d], end = row_ptr[d + 1];
    unsigned pld = xlw[(size_t)d * 64 + lane];
    unsigned prd = xrw[(size_t)d * 64 + lane];
    float xr0 = bfl(prd), xr1 = bfh(prd);
    // self-loop first (loop_attr = agg_ea/deg)
    float inv = 1.0f / fmaxf((float)(end - beg), 1.0f);
    float al_loop = edge_score((const float4*)(agg_ea + (size_t)d * 16), inv,
                               pld, xr0, xr1, w0, w1, a0, a1);
    float m_run = al_loop, l_run = 1.0f;
    float n0 = bfl(pld), n1 = bfh(pld);
    int i = beg;
    for (; i + 3 < end; i += 4) {
        int s0 = rfl(csr_src[i]),     s1 = rfl(csr_src[i + 1]);
        int s2 = rfl(csr_src[i + 2]), s3 = rfl(csr_src[i + 3]);
        int e0 = rfl(csr_eid[i]),     e1 = rfl(csr_eid[i + 1]);
        int e2 = rfl(csr_eid[i + 2]), e3 = rfl(csr_eid[i + 3]);
        unsigned p0 = xlw[(size_t)s0 * 64 + lane];
        unsigned p1 = xlw[(size_t)s1 * 64 + lane];
        unsigned p2 = xlw[(size_t)s2 * 64 + lane];
        unsigned p3 = xlw[(size_t)s3 * 64 + lane];
        float al0 = edge_score((const float4*)(eattr + (size_t)e0 * 16), 1.0f, p0, xr0, xr1, w0, w1, a0, a1);
        float al1 = edge_score((const float4*)(eattr + (size_t)e1 * 16), 1.0f, p1, xr0, xr1, w0, w1, a0, a1);
        float al2 = edge_score((const float4*)(eattr + (size_t)e2 * 16), 1.0f, p2, xr0, xr1, w0, w1, a0, a1);
        float al3 = edge_score((const float4*)(eattr + (size_t)e3 * 16), 1.0f, p3, xr0, xr1, w0, w1, a0, a1);
        online_upd(al0, p0, m_run, l_run, n0, n1);
        online_upd(al1, p1, m_run, l_run, n0, n1);
        online_upd(al2, p2, m_run, l_run, n0, n1);
        online_upd(al3, p3, m_run, l_run, n0, n1);
    }
    for (; i < end; ++i) {
        int s = rfl(csr_src[i]);
        int e = rfl(csr_eid[i]);
        unsigned p = xlw[(size_t)s * 64 + lane];
        float al = edge_score((const float4*)(eattr + (size_t)e * 16), 1.0f, p, xr0, xr1, w0, w1, a0, a1);
        online_upd(al, p, m_run, l_run, n0, n1);
    }
    float rinv = 1.0f / l_run;
    float2 bv = *(const float2*)(bias2 + 2 * lane);
    float o0 = n0 * rinv + bv.x;
    float o1 = n1 * rinv + bv.y;
    int g = batch[d];
    atomAddF(&gsum[(size_t)g * 128 + 2 * lane], o0);
    atomAddF(&gsum[(size_t)g * 128 + 2 * lane + 1], o1);
    if (lane == 0) atomAddF(&cnt[g], 1.0f);
}

// ---------------- Kernel G: FFN ----------------------------------------------
__global__ __launch_bounds__(256) void k_ffn(
    const float* __restrict__ gsum, const float* __restrict__ cnt,
    const float* __restrict__ W1, const float* __restrict__ b1,
    const float* __restrict__ W2, const float* __restrict__ b2,
    float* __restrict__ y) {
    __shared__ float row[128];
    __shared__ float red[4];
    int g = blockIdx.x;
    int t = threadIdx.x;
    if (t < 128) row[t] = gsum[(size_t)g * 128 + t] / fmaxf(cnt[g], 1.0f);
    __syncthreads();
    float part = 0.f;
    #pragma unroll
    for (int jj = 0; jj < 2; ++jj) {
        int j = t + jj * 256;
        float acc = b1[j];
        for (int k = 0; k < 128; ++k) acc += row[k] * W1[k * 512 + j];
        part += gelu_t(acc) * W2[j];
    }
    #pragma unroll
    for (int off = 32; off; off >>= 1) part += __shfl_xor(part, off, 64);
    if ((t & 63) == 0) red[t >> 6] = part;
    __syncthreads();
    if (t == 0) y[g] = red[0] + red[1] + red[2] + red[3] + b2[0];
}

extern "C" void kernel_launch(void* const* d_in, const int* in_sizes, int n_in,
                              void* d_out, int out_size, void* d_ws, size_t ws_size,
                              hipStream_t stream) {
    const float* x      = (const float*)d_in[0];
    const int*   eidx   = (const int*)d_in[1];
    const float* eattr  = (const float*)d_in[2];
    const int*   batch  = (const int*)d_in[3];
    const float* W_msg  = (const float*)d_in[4];
    const float* b_msg  = (const float*)d_in[5];
    const float* W_e1   = (const float*)d_in[6];
    const float* b_e1   = (const float*)d_in[7];
    const float* W_self = (const float*)d_in[8];
    const float* b_self = (const float*)d_in[9];
    const float* W_l    = (const float*)d_in[10];
    const float* b_l    = (const float*)d_in[11];
    const float* W_r    = (const float*)d_in[12];
    const float* b_r    = (const float*)d_in[13];
    const float* W_e2   = (const float*)d_in[14];
    const float* att    = (const float*)d_in[15];
    const float* bias2  = (const float*)d_in[16];
    const float* W1     = (const float*)d_in[17];
    const float* b1     = (const float*)d_in[18];
    const float* W2     = (const float*)d_in[19];
    const float* b2     = (const float*)d_in[20];
    const int* src = eidx;
    const int* dst = eidx + NE;

    char* wsb = (char*)d_ws;
    size_t o = 0;
    // --- zero region: hist, gsum, cnt ---
    int*   hist   = (int*)(wsb + o);   o += (size_t)NN * 4;
    float* gsum   = (float*)(wsb + o); o += (size_t)NG * 128 * 4;
    float* cnt    = (float*)(wsb + o); o += 4096;
    size_t zero_bytes = o;
    // --- rest (16B-aligned chunks) ---
    int*   row_ptr = (int*)(wsb + o);  o += (size_t)(NN + 4) * 4;
    int*   cursor  = (int*)(wsb + o);  o += (size_t)NN * 4;
    int*   csr_src = (int*)(wsb + o);  o += (size_t)NE * 4;
    int*   csr_eid = (int*)(wsb + o);  o += (size_t)NE * 4;
    float* agg_x   = (float*)(wsb + o); o += (size_t)NN * 64 * 4;
    float* agg_ea  = (float*)(wsb + o); o += (size_t)NN * 16 * 4;
    unsigned short* h_bf  = (unsigned short*)(wsb + o); o += (size_t)NN * 256 * 2;
    unsigned short* x_bf  = (unsigned short*)(wsb + o); o += (size_t)NN * 64 * 2;
    unsigned short* xl_bf = (unsigned short*)(wsb + o); o += (size_t)NN * 128 * 2;
    unsigned short* xr_bf = (unsigned short*)(wsb + o); o += (size_t)NN * 128 * 2;
    unsigned short* wfrag = (unsigned short*)(wsb + o); o += (size_t)8192 * 8 * 2;

    hipMemsetAsync(d_ws, 0, zero_bytes, stream);
    hipLaunchKernelGGL(k_xbf, dim3(NN * 16 / 256), dim3(256), 0, stream, x, x_bf);
    hipLaunchKernelGGL(k_wrep, dim3(32), dim3(256), 0, stream, W_l, W_r, wfrag);
    hipLaunchKernelGGL(k_hist, dim3((NE + 255) / 256), dim3(256), 0, stream, dst, hist);
    hipLaunchKernelGGL(k_scan, dim3(1), dim3(1024), 0, stream, hist, row_ptr, cursor);
    hipLaunchKernelGGL(k_scatter, dim3((NE + 255) / 256), dim3(256), 0, stream,
                       src, dst, cursor, csr_src, csr_eid);
    hipLaunchKernelGGL(k_agg, dim3((NN + 3) / 4), dim3(256), 0, stream,
                       x_bf, eattr, csr_src, csr_eid, row_ptr, agg_x, agg_ea);
    hipLaunchKernelGGL(k_h, dim3(4, 625), dim3(256), 0, stream,
                       x, agg_x, agg_ea, row_ptr, W_self, W_msg, W_e1, b_self, b_msg, b_e1, h_bf);
    hipLaunchKernelGGL(k_xlr_mfma, dim3(625), dim3(256), 0, stream,
                       h_bf, wfrag, b_l, b_r, xl_bf, xr_bf);
    hipLaunchKernelGGL(k_gat, dim3((NN + 3) / 4), dim3(256), 0, stream,
                       (const unsigned*)xl_bf, (const unsigned*)xr_bf, eattr,
                       csr_src, csr_eid, row_ptr, agg_ea, W_e2, att, bias2,
                       batch, gsum, cnt);
    hipLaunchKernelGGL(k_ffn, dim3(NG), dim3(256), 0, stream,
                       gsum, cnt, W1, b1, W2, b2, (float*)d_out);
}

// Round 6
// 515.119 us; speedup vs baseline: 2.7926x; 1.0513x over previous
//
#include <hip/hip_runtime.h>
#include <hip/hip_bf16.h>

#define NN 40000
#define NE 640000
#define NG 1000

typedef __attribute__((ext_vector_type(8))) short short8;
typedef __attribute__((ext_vector_type(4))) float f32x4;

__device__ __forceinline__ float gelu_t(float x) {
    float u = 0.7978845608028654f * (x + 0.044715f * x * x * x);
    return 0.5f * x * (1.0f + tanhf(u));
}
__device__ __forceinline__ void atomAddF(float* p, float v) {
    unsafeAtomicAdd(p, v);
}
__device__ __forceinline__ int rfl(int v) { return __builtin_amdgcn_readfirstlane(v); }
__device__ __forceinline__ unsigned short f2bf(float f) {
    unsigned u = __float_as_uint(f);
    unsigned r = (u + 0x7fffu + ((u >> 16) & 1u)) >> 16;
    return (unsigned short)r;
}
__device__ __forceinline__ unsigned pk_bf(float lo, float hi) {
    __hip_bfloat162 v = __float22bfloat162_rn(make_float2(lo, hi));
    unsigned r;
    __builtin_memcpy(&r, &v, 4);
    return r;
}
__device__ __forceinline__ float bfl(unsigned p) { return __uint_as_float(p << 16); }
__device__ __forceinline__ float bfh(unsigned p) { return __uint_as_float(p & 0xffff0000u); }

// ---------------- Kernel P: fused x->bf16 cast + dst histogram + W repack ----
// grid 2500 x 256 = 640000 threads exactly (= NN*16 float4 chunks = NE edges)
__global__ __launch_bounds__(256) void k_pre(
    const float* __restrict__ x, const int* __restrict__ dst,
    const float* __restrict__ W_l, const float* __restrict__ W_r,
    unsigned short* __restrict__ x_bf, int* __restrict__ hist,
    unsigned short* __restrict__ wfrag) {
    int t = blockIdx.x * 256 + threadIdx.x;
    // x cast (NN*16 = 640000 float4 chunks)
    float4 v = ((const float4*)x)[t];
    ((uint2*)x_bf)[t] = make_uint2(pk_bf(v.x, v.y), pk_bf(v.z, v.w));
    // histogram
    atomicAdd(&hist[dst[t]], 1);
    // W_l|W_r -> MFMA B-fragment repack (8192 threads)
    if (t < 8192) {
        int l = t & 63;
        int kt = (t >> 6) & 7;
        int nt = t >> 9;
        int n = nt * 16 + (l & 15);
        int k0 = kt * 32 + (l >> 4) * 8;
        const float* W = (n < 128) ? W_l : W_r;
        int nn = n & 127;
        float w[8];
        #pragma unroll
        for (int j = 0; j < 8; ++j) w[j] = W[(size_t)(k0 + j) * 128 + nn];
        uint4 pack;
        pack.x = pk_bf(w[0], w[1]);
        pack.y = pk_bf(w[2], w[3]);
        pack.z = pk_bf(w[4], w[5]);
        pack.w = pk_bf(w[6], w[7]);
        ((uint4*)wfrag)[t] = pack;
    }
}

// ---------------- CSR build: single-block exclusive scan ---------------------
__global__ __launch_bounds__(1024) void k_scan(const int* __restrict__ hist,
                                               int* __restrict__ row_ptr,
                                               int* __restrict__ cursor) {
    __shared__ int ssum[1024];
    int t = threadIdx.x;
    int base = t * 40;
    int local[40];
    int s = 0;
    #pragma unroll
    for (int j = 0; j < 40; ++j) {
        int idx = base + j;
        int v = (idx < NN) ? hist[idx] : 0;
        local[j] = s;
        s += v;
    }
    ssum[t] = s;
    __syncthreads();
    for (int off = 1; off < 1024; off <<= 1) {
        int tmp = (t >= off) ? ssum[t - off] : 0;
        __syncthreads();
        ssum[t] += tmp;
        __syncthreads();
    }
    int prefix = (t > 0) ? ssum[t - 1] : 0;
    #pragma unroll
    for (int j = 0; j < 40; ++j) {
        int idx = base + j;
        if (idx < NN) {
            int v = prefix + local[j];
            row_ptr[idx] = v;
            cursor[idx] = v;
        }
    }
    if (t == 0) row_ptr[NN] = NE;
}

// ---------------- CSR build: scatter src + bf16 edge-attr reorder ------------
__global__ __launch_bounds__(256) void k_scatter(const int* __restrict__ src,
                                                 const int* __restrict__ dst,
                                                 const float* __restrict__ eattr,
                                                 int* __restrict__ cursor,
                                                 int* __restrict__ csr_src,
                                                 unsigned short* __restrict__ ea_csr) {
    int e = blockIdx.x * 256 + threadIdx.x;
    if (e >= NE) return;
    int d = dst[e];
    int pos = atomicAdd(&cursor[d], 1);
    csr_src[pos] = src[e];
    const float4* ep = (const float4*)(eattr + (size_t)e * 16);
    float4 a = ep[0], b = ep[1], c = ep[2], dd = ep[3];
    uint4 q0, q1;
    q0.x = pk_bf(a.x, a.y); q0.y = pk_bf(a.z, a.w);
    q0.z = pk_bf(b.x, b.y); q0.w = pk_bf(b.z, b.w);
    q1.x = pk_bf(c.x, c.y); q1.y = pk_bf(c.z, c.w);
    q1.z = pk_bf(dd.x, dd.y); q1.w = pk_bf(dd.z, dd.w);
    uint4* out = (uint4*)ea_csr;
    out[(size_t)pos * 2]     = q0;
    out[(size_t)pos * 2 + 1] = q1;
}

// ---------------- Kernel A: per-dst gather aggregation -----------------------
// wave per dst. x gathered by half-waves (dword/lane); ea summed from the
// flat sequential ea_csr region.
__global__ __launch_bounds__(256) void k_agg(
    const unsigned short* __restrict__ x_bf, const unsigned short* __restrict__ ea_csr,
    const int* __restrict__ csr_src, const int* __restrict__ row_ptr,
    float* __restrict__ agg_x, float* __restrict__ agg_ea) {
    int d = rfl(blockIdx.x * 4 + (threadIdx.x >> 6));
    int lane = threadIdx.x & 63;
    if (d >= NN) return;
    int beg = row_ptr[d], end = row_ptr[d + 1];
    const unsigned* xw = (const unsigned*)x_bf;
    const unsigned* eaw = (const unsigned*)ea_csr;
    int h = lane >> 5;
    int c2 = lane & 31;
    // --- x: half-wave per edge, 2 cols/lane, unroll 2 per half (4 in flight)
    float sxa0 = 0.f, sxa1 = 0.f, sxb0 = 0.f, sxb1 = 0.f;
    int i = beg + h;
    for (; i + 2 < end; i += 4) {
        int sA = csr_src[i];
        int sB = csr_src[i + 2];
        unsigned wA = xw[(size_t)sA * 32 + c2];
        unsigned wB = xw[(size_t)sB * 32 + c2];
        sxa0 += bfl(wA); sxa1 += bfh(wA);
        sxb0 += bfl(wB); sxb1 += bfh(wB);
    }
    if (i < end) {
        int s = csr_src[i];
        unsigned w = xw[(size_t)s * 32 + c2];
        sxa0 += bfl(w); sxa1 += bfh(w);
    }
    float sx0 = sxa0 + sxb0, sx1 = sxa1 + sxb1;
    sx0 += __shfl_xor(sx0, 32, 64);
    sx1 += __shfl_xor(sx1, 32, 64);
    // --- ea: flat sequential sum; uint p covers cols (2*(p&7), +1)
    float se0 = 0.f, se1 = 0.f, se0b = 0.f, se1b = 0.f;
    int p = beg * 8 + lane;
    int pend = end * 8;
    for (; p + 64 < pend; p += 128) {
        unsigned w = eaw[p];
        unsigned w2 = eaw[p + 64];
        se0 += bfl(w); se1 += bfh(w);
        se0b += bfl(w2); se1b += bfh(w2);
    }
    if (p < pend) {
        unsigned w = eaw[p];
        se0 += bfl(w); se1 += bfh(w);
    }
    se0 += se0b; se1 += se1b;
    #pragma unroll
    for (int off = 8; off < 64; off <<= 1) {
        se0 += __shfl_xor(se0, off, 64);
        se1 += __shfl_xor(se1, off, 64);
    }
    if (h == 0) ((float2*)agg_x)[(size_t)d * 32 + c2] = make_float2(sx0, sx1);
    if (lane < 8) ((float2*)agg_ea)[(size_t)d * 8 + lane] = make_float2(se0, se1);
}

// ---------------- Kernel B: h = gelu(concatA @ concatW + biases), bf16 out ---
__global__ __launch_bounds__(256) void k_h(
    const float* __restrict__ x, const float* __restrict__ agg_x,
    const float* __restrict__ agg_ea, const int* __restrict__ row_ptr,
    const float* __restrict__ W_self, const float* __restrict__ W_msg,
    const float* __restrict__ W_e1, const float* __restrict__ b_self,
    const float* __restrict__ b_msg, const float* __restrict__ b_e1,
    unsigned short* __restrict__ h_bf) {
    __shared__ float As[16][64];
    __shared__ float Bs[16][64];
    int bx = blockIdx.x;
    int by = blockIdx.y;
    int t = threadIdx.x;
    int tx = t & 15, ty = t >> 4;
    int li = t >> 2;
    int lk4 = (t & 3) * 4;
    int lc = t & 63;
    int lkb = t >> 6;
    float acc[4][4] = {};
    for (int kt = 0; kt < 9; ++kt) {
        const float* asrc; int stride; int kbase;
        if (kt < 4)      { asrc = x;      stride = 64; kbase = kt * 16; }
        else if (kt < 8) { asrc = agg_x;  stride = 64; kbase = (kt - 4) * 16; }
        else             { asrc = agg_ea; stride = 16; kbase = 0; }
        int n = by * 64 + li;
        float4 av = *(const float4*)(asrc + (size_t)n * stride + kbase + lk4);
        As[lk4 + 0][li] = av.x; As[lk4 + 1][li] = av.y;
        As[lk4 + 2][li] = av.z; As[lk4 + 3][li] = av.w;
        const float* bsrc;
        if (kt < 4)      bsrc = W_self + kt * 16 * 256;
        else if (kt < 8) bsrc = W_msg + (kt - 4) * 16 * 256;
        else             bsrc = W_e1;
        #pragma unroll
        for (int j = 0; j < 4; ++j) {
            int kk = lkb + j * 4;
            Bs[kk][lc] = bsrc[kk * 256 + bx * 64 + lc];
        }
        __syncthreads();
        #pragma unroll
        for (int k = 0; k < 16; ++k) {
            float4 a = *(const float4*)&As[k][ty * 4];
            float4 b = *(const float4*)&Bs[k][tx * 4];
            acc[0][0] += a.x * b.x; acc[0][1] += a.x * b.y; acc[0][2] += a.x * b.z; acc[0][3] += a.x * b.w;
            acc[1][0] += a.y * b.x; acc[1][1] += a.y * b.y; acc[1][2] += a.y * b.z; acc[1][3] += a.y * b.w;
            acc[2][0] += a.z * b.x; acc[2][1] += a.z * b.y; acc[2][2] += a.z * b.z; acc[2][3] += a.z * b.w;
            acc[3][0] += a.w * b.x; acc[3][1] += a.w * b.y; acc[3][2] += a.w * b.z; acc[3][3] += a.w * b.w;
        }
        __syncthreads();
    }
    int c0 = bx * 64 + tx * 4;
    #pragma unroll
    for (int r = 0; r < 4; ++r) {
        int n = by * 64 + ty * 4 + r;
        float dg = (float)(row_ptr[n + 1] - row_ptr[n]);
        float v[4];
        #pragma unroll
        for (int cc = 0; cc < 4; ++cc) {
            int c = c0 + cc;
            v[cc] = gelu_t(acc[r][cc] + b_self[c] + dg * (b_msg[c] + b_e1[c]));
        }
        ((uint2*)h_bf)[(size_t)n * 64 + (c0 >> 2)] =
            make_uint2(pk_bf(v[0], v[1]), pk_bf(v[2], v[3]));
    }
}

// ---------------- Kernel C: xl/xr via bf16 MFMA ------------------------------
__global__ __launch_bounds__(256) void k_xlr_mfma(
    const unsigned short* __restrict__ h_bf, const unsigned short* __restrict__ wfrag,
    const float* __restrict__ b_l, const float* __restrict__ b_r,
    unsigned short* __restrict__ xl_bf, unsigned short* __restrict__ xr_bf) {
    int w = threadIdx.x >> 6;
    int l = threadIdx.x & 63;
    int m0 = blockIdx.x * 64;
    int quad = l >> 4, lm = l & 15;
    f32x4 acc[4][4] = {};   // [mt][nt]
    for (int kt = 0; kt < 8; ++kt) {
        short8 a[4], b[4];
        #pragma unroll
        for (int mt = 0; mt < 4; ++mt) {
            int row = m0 + mt * 16 + lm;
            a[mt] = *(const short8*)(h_bf + (size_t)row * 256 + kt * 32 + quad * 8);
        }
        #pragma unroll
        for (int nt = 0; nt < 4; ++nt) {
            int gnt = w * 4 + nt;
            b[nt] = *(const short8*)(wfrag + (((size_t)(gnt * 8 + kt) * 64 + l) * 8));
        }
        #pragma unroll
        for (int mt = 0; mt < 4; ++mt)
            #pragma unroll
            for (int nt = 0; nt < 4; ++nt)
                acc[mt][nt] = __builtin_amdgcn_mfma_f32_16x16x32_bf16(a[mt], b[nt], acc[mt][nt], 0, 0, 0);
    }
    bool isl = (w < 2);
    unsigned short* outp = isl ? xl_bf : xr_bf;
    int colbase = isl ? w * 64 : (w - 2) * 64;
    const float* bias = isl ? b_l : b_r;
    #pragma unroll
    for (int nt = 0; nt < 4; ++nt) {
        int col = colbase + nt * 16 + lm;
        float bv = bias[col];
        #pragma unroll
        for (int mt = 0; mt < 4; ++mt) {
            #pragma unroll
            for (int r = 0; r < 4; ++r) {
                int row = m0 + mt * 16 + quad * 4 + r;
                outp[(size_t)row * 128 + col] = f2bf(acc[mt][nt][r] + bv);
            }
        }
    }
}

// ---------------- edge score helper ------------------------------------------
__device__ __forceinline__ float edge_score(const float* eav,
                                            unsigned pl, float xr0, float xr1,
                                            const float* w0, const float* w1,
                                            float a0, float a1) {
    float m0 = bfl(pl) + xr0, m1 = bfh(pl) + xr1;
    #pragma unroll
    for (int j = 0; j < 16; ++j) { m0 += eav[j] * w0[j]; m1 += eav[j] * w1[j]; }
    m0 = (m0 > 0.f) ? m0 : 0.2f * m0;
    m1 = (m1 > 0.f) ? m1 : 0.2f * m1;
    float part = m0 * a0 + m1 * a1;
    #pragma unroll
    for (int off = 32; off; off >>= 1) part += __shfl_xor(part, off, 64);
    return part;
}

__device__ __forceinline__ void unp16(uint4 q0, uint4 q1, float* eav) {
    eav[0] = bfl(q0.x); eav[1] = bfh(q0.x); eav[2] = bfl(q0.y); eav[3] = bfh(q0.y);
    eav[4] = bfl(q0.z); eav[5] = bfh(q0.z); eav[6] = bfl(q0.w); eav[7] = bfh(q0.w);
    eav[8] = bfl(q1.x); eav[9] = bfh(q1.x); eav[10] = bfl(q1.y); eav[11] = bfh(q1.y);
    eav[12] = bfl(q1.z); eav[13] = bfh(q1.z); eav[14] = bfl(q1.w); eav[15] = bfh(q1.w);
}

__device__ __forceinline__ void online_upd(float al, unsigned p, float& m_run,
                                           float& l_run, float& n0, float& n1) {
    if (al > m_run) {   // rare; al is wave-uniform -> cheap branch
        float sc = __expf(m_run - al);
        l_run *= sc; n0 *= sc; n1 *= sc;
        m_run = al;
    }
    float wgt = __expf(al - m_run);
    l_run += wgt;
    n0 += wgt * bfl(p);
    n1 += wgt * bfh(p);
}

// ---------------- Kernel D: fused per-dst GATv2 (score+softmax+accum+pool) ---
__global__ __launch_bounds__(256) void k_gat(
    const unsigned* __restrict__ xlw, const unsigned* __restrict__ xrw,
    const unsigned short* __restrict__ ea_csr, const int* __restrict__ csr_src,
    const int* __restrict__ row_ptr, const float* __restrict__ agg_ea,
    const float* __restrict__ W_e2, const float* __restrict__ att,
    const float* __restrict__ bias2, const int* __restrict__ batch,
    float* __restrict__ gsum, float* __restrict__ cnt) {
    int d = rfl(blockIdx.x * 4 + (threadIdx.x >> 6));
    int lane = threadIdx.x & 63;
    if (d >= NN) return;
    float w0[16], w1[16];
    #pragma unroll
    for (int j = 0; j < 16; ++j) {
        float2 wv = *(const float2*)(W_e2 + j * 128 + 2 * lane);
        w0[j] = wv.x; w1[j] = wv.y;
    }
    float2 av = *(const float2*)(att + 2 * lane);
    float a0 = av.x, a1 = av.y;
    int beg = row_ptr[d], end = row_ptr[d + 1];
    const uint4* eap = (const uint4*)ea_csr;
    unsigned pld = xlw[(size_t)d * 64 + lane];
    unsigned prd = xrw[(size_t)d * 64 + lane];
    float xr0 = bfl(prd), xr1 = bfh(prd);
    // self-loop first (loop_attr = agg_ea/deg)
    float inv = 1.0f / fmaxf((float)(end - beg), 1.0f);
    float eavl[16];
    {
        const float4* ep = (const float4*)(agg_ea + (size_t)d * 16);
        float4 e0 = ep[0], e1 = ep[1], e2 = ep[2], e3 = ep[3];
        eavl[0]=e0.x*inv; eavl[1]=e0.y*inv; eavl[2]=e0.z*inv; eavl[3]=e0.w*inv;
        eavl[4]=e1.x*inv; eavl[5]=e1.y*inv; eavl[6]=e1.z*inv; eavl[7]=e1.w*inv;
        eavl[8]=e2.x*inv; eavl[9]=e2.y*inv; eavl[10]=e2.z*inv; eavl[11]=e2.w*inv;
        eavl[12]=e3.x*inv; eavl[13]=e3.y*inv; eavl[14]=e3.z*inv; eavl[15]=e3.w*inv;
    }
    float al_loop = edge_score(eavl, pld, xr0, xr1, w0, w1, a0, a1);
    float m_run = al_loop, l_run = 1.0f;
    float n0 = bfl(pld), n1 = bfh(pld);
    int i = beg;
    for (; i + 3 < end; i += 4) {
        int s0 = rfl(csr_src[i]),     s1 = rfl(csr_src[i + 1]);
        int s2 = rfl(csr_src[i + 2]), s3 = rfl(csr_src[i + 3]);
        uint4 qa0 = eap[(size_t)i * 2],       qa1 = eap[(size_t)i * 2 + 1];
        uint4 qb0 = eap[(size_t)(i + 1) * 2], qb1 = eap[(size_t)(i + 1) * 2 + 1];
        uint4 qc0 = eap[(size_t)(i + 2) * 2], qc1 = eap[(size_t)(i + 2) * 2 + 1];
        uint4 qd0 = eap[(size_t)(i + 3) * 2], qd1 = eap[(size_t)(i + 3) * 2 + 1];
        unsigned p0 = xlw[(size_t)s0 * 64 + lane];
        unsigned p1 = xlw[(size_t)s1 * 64 + lane];
        unsigned p2 = xlw[(size_t)s2 * 64 + lane];
        unsigned p3 = xlw[(size_t)s3 * 64 + lane];
        float ea0[16], ea1[16], ea2[16], ea3[16];
        unp16(qa0, qa1, ea0); unp16(qb0, qb1, ea1);
        unp16(qc0, qc1, ea2); unp16(qd0, qd1, ea3);
        float al0 = edge_score(ea0, p0, xr0, xr1, w0, w1, a0, a1);
        float al1 = edge_score(ea1, p1, xr0, xr1, w0, w1, a0, a1);
        float al2 = edge_score(ea2, p2, xr0, xr1, w0, w1, a0, a1);
        float al3 = edge_score(ea3, p3, xr0, xr1, w0, w1, a0, a1);
        online_upd(al0, p0, m_run, l_run, n0, n1);
        online_upd(al1, p1, m_run, l_run, n0, n1);
        online_upd(al2, p2, m_run, l_run, n0, n1);
        online_upd(al3, p3, m_run, l_run, n0, n1);
    }
    for (; i < end; ++i) {
        int s = rfl(csr_src[i]);
        uint4 q0 = eap[(size_t)i * 2], q1 = eap[(size_t)i * 2 + 1];
        unsigned p = xlw[(size_t)s * 64 + lane];
        float ea[16];
        unp16(q0, q1, ea);
        float al = edge_score(ea, p, xr0, xr1, w0, w1, a0, a1);
        online_upd(al, p, m_run, l_run, n0, n1);
    }
    float rinv = 1.0f / l_run;
    float2 bv = *(const float2*)(bias2 + 2 * lane);
    float o0 = n0 * rinv + bv.x;
    float o1 = n1 * rinv + bv.y;
    int g = batch[d];
    atomAddF(&gsum[(size_t)g * 128 + 2 * lane], o0);
    atomAddF(&gsum[(size_t)g * 128 + 2 * lane + 1], o1);
    if (lane == 0) atomAddF(&cnt[g], 1.0f);
}

// ---------------- Kernel G: FFN ----------------------------------------------
__global__ __launch_bounds__(256) void k_ffn(
    const float* __restrict__ gsum, const float* __restrict__ cnt,
    const float* __restrict__ W1, const float* __restrict__ b1,
    const float* __restrict__ W2, const float* __restrict__ b2,
    float* __restrict__ y) {
    __shared__ float row[128];
    __shared__ float red[4];
    int g = blockIdx.x;
    int t = threadIdx.x;
    if (t < 128) row[t] = gsum[(size_t)g * 128 + t] / fmaxf(cnt[g], 1.0f);
    __syncthreads();
    float part = 0.f;
    #pragma unroll
    for (int jj = 0; jj < 2; ++jj) {
        int j = t + jj * 256;
        float acc = b1[j];
        for (int k = 0; k < 128; ++k) acc += row[k] * W1[k * 512 + j];
        part += gelu_t(acc) * W2[j];
    }
    #pragma unroll
    for (int off = 32; off; off >>= 1) part += __shfl_xor(part, off, 64);
    if ((t & 63) == 0) red[t >> 6] = part;
    __syncthreads();
    if (t == 0) y[g] = red[0] + red[1] + red[2] + red[3] + b2[0];
}

extern "C" void kernel_launch(void* const* d_in, const int* in_sizes, int n_in,
                              void* d_out, int out_size, void* d_ws, size_t ws_size,
                              hipStream_t stream) {
    const float* x      = (const float*)d_in[0];
    const int*   eidx   = (const int*)d_in[1];
    const float* eattr  = (const float*)d_in[2];
    const int*   batch  = (const int*)d_in[3];
    const float* W_msg  = (const float*)d_in[4];
    const float* b_msg  = (const float*)d_in[5];
    const float* W_e1   = (const float*)d_in[6];
    const float* b_e1   = (const float*)d_in[7];
    const float* W_self = (const float*)d_in[8];
    const float* b_self = (const float*)d_in[9];
    const float* W_l    = (const float*)d_in[10];
    const float* b_l    = (const float*)d_in[11];
    const float* W_r    = (const float*)d_in[12];
    const float* b_r    = (const float*)d_in[13];
    const float* W_e2   = (const float*)d_in[14];
    const float* att    = (const float*)d_in[15];
    const float* bias2  = (const float*)d_in[16];
    const float* W1     = (const float*)d_in[17];
    const float* b1     = (const float*)d_in[18];
    const float* W2     = (const float*)d_in[19];
    const float* b2     = (const float*)d_in[20];
    const int* src = eidx;
    const int* dst = eidx + NE;

    char* wsb = (char*)d_ws;
    size_t o = 0;
    // --- zero region: hist, gsum, cnt ---
    int*   hist   = (int*)(wsb + o);   o += (size_t)NN * 4;
    float* gsum   = (float*)(wsb + o); o += (size_t)NG * 128 * 4;
    float* cnt    = (float*)(wsb + o); o += 4096;
    size_t zero_bytes = o;
    // --- rest (16B-aligned chunks) ---
    int*   row_ptr = (int*)(wsb + o);  o += (size_t)(NN + 4) * 4;
    int*   cursor  = (int*)(wsb + o);  o += (size_t)NN * 4;
    int*   csr_src = (int*)(wsb + o);  o += (size_t)NE * 4;
    unsigned short* ea_csr = (unsigned short*)(wsb + o); o += (size_t)NE * 16 * 2;
    float* agg_x   = (float*)(wsb + o); o += (size_t)NN * 64 * 4;
    float* agg_ea  = (float*)(wsb + o); o += (size_t)NN * 16 * 4;
    unsigned short* h_bf  = (unsigned short*)(wsb + o); o += (size_t)NN * 256 * 2;
    unsigned short* x_bf  = (unsigned short*)(wsb + o); o += (size_t)NN * 64 * 2;
    unsigned short* xl_bf = (unsigned short*)(wsb + o); o += (size_t)NN * 128 * 2;
    unsigned short* xr_bf = (unsigned short*)(wsb + o); o += (size_t)NN * 128 * 2;
    unsigned short* wfrag = (unsigned short*)(wsb + o); o += (size_t)8192 * 8 * 2;

    hipMemsetAsync(d_ws, 0, zero_bytes, stream);
    hipLaunchKernelGGL(k_pre, dim3(2500), dim3(256), 0, stream,
                       x, dst, W_l, W_r, x_bf, hist, wfrag);
    hipLaunchKernelGGL(k_scan, dim3(1), dim3(1024), 0, stream, hist, row_ptr, cursor);
    hipLaunchKernelGGL(k_scatter, dim3(2500), dim3(256), 0, stream,
                       src, dst, eattr, cursor, csr_src, ea_csr);
    hipLaunchKernelGGL(k_agg, dim3((NN + 3) / 4), dim3(256), 0, stream,
                       x_bf, ea_csr, csr_src, row_ptr, agg_x, agg_ea);
    hipLaunchKernelGGL(k_h, dim3(4, 625), dim3(256), 0, stream,
                       x, agg_x, agg_ea, row_ptr, W_self, W_msg, W_e1, b_self, b_msg, b_e1, h_bf);
    hipLaunchKernelGGL(k_xlr_mfma, dim3(625), dim3(256), 0, stream,
                       h_bf, wfrag, b_l, b_r, xl_bf, xr_bf);
    hipLaunchKernelGGL(k_gat, dim3((NN + 3) / 4), dim3(256), 0, stream,
                       (const unsigned*)xl_bf, (const unsigned*)xr_bf, ea_csr,
                       csr_src, row_ptr, agg_ea, W_e2, att, bias2,
                       batch, gsum, cnt);
    hipLaunchKernelGGL(k_ffn, dim3(NG), dim3(256), 0, stream,
                       gsum, cnt, W1, b1, W2, b2, (float*)d_out);
}

// Round 7
// 465.133 us; speedup vs baseline: 3.0927x; 1.1075x over previous
//
#include <hip/hip_runtime.h>
#include <hip/hip_bf16.h>

#define NN 40000
#define NE 640000
#define NG 1000

typedef __attribute__((ext_vector_type(8))) short short8;
typedef __attribute__((ext_vector_type(4))) float f32x4;

__device__ __forceinline__ float gelu_t(float x) {
    float u = 0.7978845608028654f * (x + 0.044715f * x * x * x);
    return 0.5f * x * (1.0f + tanhf(u));
}
__device__ __forceinline__ void atomAddF(float* p, float v) {
    unsafeAtomicAdd(p, v);
}
__device__ __forceinline__ int rfl(int v) { return __builtin_amdgcn_readfirstlane(v); }
__device__ __forceinline__ unsigned short f2bf(float f) {
    unsigned u = __float_as_uint(f);
    unsigned r = (u + 0x7fffu + ((u >> 16) & 1u)) >> 16;
    return (unsigned short)r;
}
__device__ __forceinline__ unsigned pk_bf(float lo, float hi) {
    __hip_bfloat162 v = __float22bfloat162_rn(make_float2(lo, hi));
    unsigned r;
    __builtin_memcpy(&r, &v, 4);
    return r;
}
__device__ __forceinline__ float bfl(unsigned p) { return __uint_as_float(p << 16); }
__device__ __forceinline__ float bfh(unsigned p) { return __uint_as_float(p & 0xffff0000u); }

// ---------------- Kernel P: x->bf16 + histogram + weight fragment packs ------
// grid 2500 x 256 = 640000 threads (= NN*16 float4 chunks = NE edges)
__global__ __launch_bounds__(256) void k_pre(
    const float* __restrict__ x, const int* __restrict__ dst,
    const float* __restrict__ W_self, const float* __restrict__ W_msg,
    const float* __restrict__ W_e1, const float* __restrict__ b_msg,
    const float* __restrict__ b_e1,
    const float* __restrict__ W_l, const float* __restrict__ W_r,
    unsigned short* __restrict__ x_bf, int* __restrict__ hist,
    unsigned short* __restrict__ wf1, unsigned short* __restrict__ wf2,
    float* __restrict__ bsum2) {
    int t = blockIdx.x * 256 + threadIdx.x;
    // x cast
    float4 v = ((const float4*)x)[t];
    ((uint2*)x_bf)[t] = make_uint2(pk_bf(v.x, v.y), pk_bf(v.z, v.w));
    // dst histogram
    atomicAdd(&hist[dst[t]], 1);
    // bsum2
    if (t < 256) bsum2[t] = b_msg[t] + b_e1[t];
    // wf1: Wcat1 [160 x 256] = [W_self; W_msg; W_e1; zeros] -> B-frag layout
    if (t < 5120) {
        int l = t & 63;
        int kt = (t >> 6) % 5;
        int gnt = t / 320;                 // 0..15
        int n = gnt * 16 + (l & 15);
        int k0 = kt * 32 + (l >> 4) * 8;
        unsigned short vv[8];
        #pragma unroll
        for (int j = 0; j < 8; ++j) {
            int k = k0 + j;
            float wv;
            if (k < 64)       wv = W_self[(size_t)k * 256 + n];
            else if (k < 128) wv = W_msg[(size_t)(k - 64) * 256 + n];
            else if (k < 144) wv = W_e1[(size_t)(k - 128) * 256 + n];
            else              wv = 0.f;
            vv[j] = f2bf(wv);
        }
        uint4 pack;
        pack.x = (unsigned)vv[0] | ((unsigned)vv[1] << 16);
        pack.y = (unsigned)vv[2] | ((unsigned)vv[3] << 16);
        pack.z = (unsigned)vv[4] | ((unsigned)vv[5] << 16);
        pack.w = (unsigned)vv[6] | ((unsigned)vv[7] << 16);
        ((uint4*)wf1)[t] = pack;
    }
    // wf2: Wcat2 [256 x 256] = [W_l | W_r] -> B-frag layout
    if (t >= 5120 && t < 13312) {
        int t2 = t - 5120;
        int l = t2 & 63;
        int kt = (t2 >> 6) & 7;
        int gnt = t2 >> 9;                 // 0..15
        int n = gnt * 16 + (l & 15);
        int k0 = kt * 32 + (l >> 4) * 8;
        const float* W = (n < 128) ? W_l : W_r;
        int nn = n & 127;
        float w[8];
        #pragma unroll
        for (int j = 0; j < 8; ++j) w[j] = W[(size_t)(k0 + j) * 128 + nn];
        uint4 pack;
        pack.x = pk_bf(w[0], w[1]);
        pack.y = pk_bf(w[2], w[3]);
        pack.z = pk_bf(w[4], w[5]);
        pack.w = pk_bf(w[6], w[7]);
        ((uint4*)wf2)[t2] = pack;
    }
}

// ---------------- CSR build: single-block exclusive scan ---------------------
__global__ __launch_bounds__(1024) void k_scan(const int* __restrict__ hist,
                                               int* __restrict__ row_ptr,
                                               int* __restrict__ cursor) {
    __shared__ int ssum[1024];
    int t = threadIdx.x;
    int base = t * 40;
    int local[40];
    int s = 0;
    #pragma unroll
    for (int j = 0; j < 40; ++j) {
        int idx = base + j;
        int v = (idx < NN) ? hist[idx] : 0;
        local[j] = s;
        s += v;
    }
    ssum[t] = s;
    __syncthreads();
    for (int off = 1; off < 1024; off <<= 1) {
        int tmp = (t >= off) ? ssum[t - off] : 0;
        __syncthreads();
        ssum[t] += tmp;
        __syncthreads();
    }
    int prefix = (t > 0) ? ssum[t - 1] : 0;
    #pragma unroll
    for (int j = 0; j < 40; ++j) {
        int idx = base + j;
        if (idx < NN) {
            int v = prefix + local[j];
            row_ptr[idx] = v;
            cursor[idx] = v;
        }
    }
    if (t == 0) row_ptr[NN] = NE;
}

// ---------------- CSR build: scatter src + bf16 edge-attr reorder ------------
__global__ __launch_bounds__(256) void k_scatter(const int* __restrict__ src,
                                                 const int* __restrict__ dst,
                                                 const float* __restrict__ eattr,
                                                 int* __restrict__ cursor,
                                                 int* __restrict__ csr_src,
                                                 unsigned short* __restrict__ ea_csr) {
    int e = blockIdx.x * 256 + threadIdx.x;
    if (e >= NE) return;
    int d = dst[e];
    int pos = atomicAdd(&cursor[d], 1);
    csr_src[pos] = src[e];
    const float4* ep = (const float4*)(eattr + (size_t)e * 16);
    float4 a = ep[0], b = ep[1], c = ep[2], dd = ep[3];
    uint4 q0, q1;
    q0.x = pk_bf(a.x, a.y); q0.y = pk_bf(a.z, a.w);
    q0.z = pk_bf(b.x, b.y); q0.w = pk_bf(b.z, b.w);
    q1.x = pk_bf(c.x, c.y); q1.y = pk_bf(c.z, c.w);
    q1.z = pk_bf(dd.x, dd.y); q1.w = pk_bf(dd.z, dd.w);
    uint4* out = (uint4*)ea_csr;
    out[(size_t)pos * 2]     = q0;
    out[(size_t)pos * 2 + 1] = q1;
}

// ---------------- Kernel A: per-dst gather aggregation (bf16 outputs) --------
__global__ __launch_bounds__(256) void k_agg(
    const unsigned short* __restrict__ x_bf, const unsigned short* __restrict__ ea_csr,
    const int* __restrict__ csr_src, const int* __restrict__ row_ptr,
    unsigned short* __restrict__ aggx_bf, float* __restrict__ agg_ea,
    unsigned short* __restrict__ aggea_bf, float* __restrict__ degf) {
    int d = rfl(blockIdx.x * 4 + (threadIdx.x >> 6));
    int lane = threadIdx.x & 63;
    if (d >= NN) return;
    int beg = row_ptr[d], end = row_ptr[d + 1];
    const unsigned* xw = (const unsigned*)x_bf;
    const unsigned* eaw = (const unsigned*)ea_csr;
    int h = lane >> 5;
    int c2 = lane & 31;
    // --- x: half-wave per edge, 2 cols/lane
    float sxa0 = 0.f, sxa1 = 0.f, sxb0 = 0.f, sxb1 = 0.f;
    int i = beg + h;
    for (; i + 2 < end; i += 4) {
        int sA = csr_src[i];
        int sB = csr_src[i + 2];
        unsigned wA = xw[(size_t)sA * 32 + c2];
        unsigned wB = xw[(size_t)sB * 32 + c2];
        sxa0 += bfl(wA); sxa1 += bfh(wA);
        sxb0 += bfl(wB); sxb1 += bfh(wB);
    }
    if (i < end) {
        int s = csr_src[i];
        unsigned w = xw[(size_t)s * 32 + c2];
        sxa0 += bfl(w); sxa1 += bfh(w);
    }
    float sx0 = sxa0 + sxb0, sx1 = sxa1 + sxb1;
    sx0 += __shfl_xor(sx0, 32, 64);
    sx1 += __shfl_xor(sx1, 32, 64);
    // --- ea: flat sequential
    float se0 = 0.f, se1 = 0.f, se0b = 0.f, se1b = 0.f;
    int p = beg * 8 + lane;
    int pend = end * 8;
    for (; p + 64 < pend; p += 128) {
        unsigned w = eaw[p];
        unsigned w2 = eaw[p + 64];
        se0 += bfl(w); se1 += bfh(w);
        se0b += bfl(w2); se1b += bfh(w2);
    }
    if (p < pend) {
        unsigned w = eaw[p];
        se0 += bfl(w); se1 += bfh(w);
    }
    se0 += se0b; se1 += se1b;
    #pragma unroll
    for (int off = 8; off < 64; off <<= 1) {
        se0 += __shfl_xor(se0, off, 64);
        se1 += __shfl_xor(se1, off, 64);
    }
    if (h == 0) ((unsigned*)aggx_bf)[(size_t)d * 32 + c2] = pk_bf(sx0, sx1);
    if (lane < 8) {
        ((float2*)agg_ea)[(size_t)d * 8 + lane] = make_float2(se0, se1);
        ((unsigned*)aggea_bf)[(size_t)d * 8 + lane] = pk_bf(se0, se1);
    }
    if (lane == 0) degf[d] = (float)(end - beg);
}

// ---------------- Kernel HX: fused h-GEMM + xl/xr-GEMM (MFMA, LDS-staged) ----
// block = 64 rows; wave w covers output cols [w*64, w*64+64) in both stages.
__global__ __launch_bounds__(256) void k_hx(
    const unsigned short* __restrict__ x_bf, const unsigned short* __restrict__ aggx_bf,
    const unsigned short* __restrict__ aggea_bf, const float* __restrict__ degf,
    const unsigned short* __restrict__ wf1, const unsigned short* __restrict__ wf2,
    const float* __restrict__ b_self, const float* __restrict__ bsum2,
    const float* __restrict__ b_l, const float* __restrict__ b_r,
    unsigned short* __restrict__ xl_bf, unsigned short* __restrict__ xr_bf) {
    __shared__ unsigned short hs[64][264];   // +8 bf16 pad: 528B row stride
    int w = threadIdx.x >> 6;
    int l = threadIdx.x & 63;
    int m0 = blockIdx.x * 64;
    int quad = l >> 4, lm = l & 15;
    // ---- stage 1: h = gelu([x|agg_x|agg_ea] @ Wcat1 + bias) ----
    {
        f32x4 acc[4][4] = {};
        short8 z8 = {0, 0, 0, 0, 0, 0, 0, 0};
        #pragma unroll
        for (int kt = 0; kt < 5; ++kt) {
            short8 a[4], b[4];
            #pragma unroll
            for (int mt = 0; mt < 4; ++mt) {
                int row = m0 + mt * 16 + lm;
                if (kt < 2)
                    a[mt] = *(const short8*)(x_bf + (size_t)row * 64 + kt * 32 + quad * 8);
                else if (kt < 4)
                    a[mt] = *(const short8*)(aggx_bf + (size_t)row * 64 + (kt - 2) * 32 + quad * 8);
                else
                    a[mt] = (quad < 2)
                        ? *(const short8*)(aggea_bf + (size_t)row * 16 + quad * 8)
                        : z8;
            }
            #pragma unroll
            for (int nt = 0; nt < 4; ++nt)
                b[nt] = *(const short8*)(wf1 + (((size_t)(w * 4 + nt) * 5 + kt) * 64 + l) * 8);
            #pragma unroll
            for (int mt = 0; mt < 4; ++mt)
                #pragma unroll
                for (int nt = 0; nt < 4; ++nt)
                    acc[mt][nt] = __builtin_amdgcn_mfma_f32_16x16x32_bf16(a[mt], b[nt], acc[mt][nt], 0, 0, 0);
        }
        #pragma unroll
        for (int nt = 0; nt < 4; ++nt) {
            int col = w * 64 + nt * 16 + lm;
            float bs = b_self[col];
            float b2 = bsum2[col];
            #pragma unroll
            for (int mt = 0; mt < 4; ++mt) {
                float4 dg = *(const float4*)(degf + m0 + mt * 16 + quad * 4);
                #pragma unroll
                for (int r = 0; r < 4; ++r) {
                    float v = gelu_t(acc[mt][nt][r] + bs + (&dg.x)[r] * b2);
                    hs[mt * 16 + quad * 4 + r][col] = f2bf(v);
                }
            }
        }
    }
    __syncthreads();
    // ---- stage 2: xl/xr = h @ [W_l|W_r] + bias ----
    f32x4 acc2[4][4] = {};
    #pragma unroll
    for (int kt = 0; kt < 8; ++kt) {
        short8 a[4], b[4];
        #pragma unroll
        for (int mt = 0; mt < 4; ++mt)
            a[mt] = *(const short8*)(&hs[mt * 16 + lm][kt * 32 + quad * 8]);
        #pragma unroll
        for (int nt = 0; nt < 4; ++nt)
            b[nt] = *(const short8*)(wf2 + (((size_t)(w * 4 + nt) * 8 + kt) * 64 + l) * 8);
        #pragma unroll
        for (int mt = 0; mt < 4; ++mt)
            #pragma unroll
            for (int nt = 0; nt < 4; ++nt)
                acc2[mt][nt] = __builtin_amdgcn_mfma_f32_16x16x32_bf16(a[mt], b[nt], acc2[mt][nt], 0, 0, 0);
    }
    bool isl = (w < 2);
    unsigned short* outp = isl ? xl_bf : xr_bf;
    int colbase = isl ? w * 64 : (w - 2) * 64;
    const float* bias = isl ? b_l : b_r;
    #pragma unroll
    for (int nt = 0; nt < 4; ++nt) {
        int col = colbase + nt * 16 + lm;
        float bv = bias[col];
        #pragma unroll
        for (int mt = 0; mt < 4; ++mt) {
            #pragma unroll
            for (int r = 0; r < 4; ++r) {
                int row = m0 + mt * 16 + quad * 4 + r;
                outp[(size_t)row * 128 + col] = f2bf(acc2[mt][nt][r] + bv);
            }
        }
    }
}

// ---------------- edge score helper ------------------------------------------
__device__ __forceinline__ float edge_score(const float* eav,
                                            unsigned pl, float xr0, float xr1,
                                            const float* w0, const float* w1,
                                            float a0, float a1) {
    float m0 = bfl(pl) + xr0, m1 = bfh(pl) + xr1;
    #pragma unroll
    for (int j = 0; j < 16; ++j) { m0 += eav[j] * w0[j]; m1 += eav[j] * w1[j]; }
    m0 = (m0 > 0.f) ? m0 : 0.2f * m0;
    m1 = (m1 > 0.f) ? m1 : 0.2f * m1;
    float part = m0 * a0 + m1 * a1;
    #pragma unroll
    for (int off = 32; off; off >>= 1) part += __shfl_xor(part, off, 64);
    return part;
}

__device__ __forceinline__ void unp16(uint4 q0, uint4 q1, float* eav) {
    eav[0] = bfl(q0.x); eav[1] = bfh(q0.x); eav[2] = bfl(q0.y); eav[3] = bfh(q0.y);
    eav[4] = bfl(q0.z); eav[5] = bfh(q0.z); eav[6] = bfl(q0.w); eav[7] = bfh(q0.w);
    eav[8] = bfl(q1.x); eav[9] = bfh(q1.x); eav[10] = bfl(q1.y); eav[11] = bfh(q1.y);
    eav[12] = bfl(q1.z); eav[13] = bfh(q1.z); eav[14] = bfl(q1.w); eav[15] = bfh(q1.w);
}

__device__ __forceinline__ void online_upd(float al, unsigned p, float& m_run,
                                           float& l_run, float& n0, float& n1) {
    if (al > m_run) {   // wave-uniform, rarely taken
        float sc = __expf(m_run - al);
        l_run *= sc; n0 *= sc; n1 *= sc;
        m_run = al;
    }
    float wgt = __expf(al - m_run);
    l_run += wgt;
    n0 += wgt * bfl(p);
    n1 += wgt * bfh(p);
}

// ---------------- Kernel D: fused per-dst GATv2 (prefetched) -----------------
__global__ __launch_bounds__(256) void k_gat(
    const unsigned* __restrict__ xlw, const unsigned* __restrict__ xrw,
    const unsigned short* __restrict__ ea_csr, const int* __restrict__ csr_src,
    const int* __restrict__ row_ptr, const float* __restrict__ agg_ea,
    const float* __restrict__ W_e2, const float* __restrict__ att,
    const float* __restrict__ bias2, const int* __restrict__ batch,
    float* __restrict__ gsum, float* __restrict__ cnt) {
    int d = rfl(blockIdx.x * 4 + (threadIdx.x >> 6));
    int lane = threadIdx.x & 63;
    if (d >= NN) return;
    float w0[16], w1[16];
    #pragma unroll
    for (int j = 0; j < 16; ++j) {
        float2 wv = *(const float2*)(W_e2 + j * 128 + 2 * lane);
        w0[j] = wv.x; w1[j] = wv.y;
    }
    float2 av = *(const float2*)(att + 2 * lane);
    float a0 = av.x, a1 = av.y;
    int beg = row_ptr[d], end = row_ptr[d + 1];
    const uint4* eap = (const uint4*)ea_csr;
    unsigned pld = xlw[(size_t)d * 64 + lane];
    unsigned prd = xrw[(size_t)d * 64 + lane];
    float xr0 = bfl(prd), xr1 = bfh(prd);
    // self-loop
    float inv = 1.0f / fmaxf((float)(end - beg), 1.0f);
    float eavl[16];
    {
        const float4* ep = (const float4*)(agg_ea + (size_t)d * 16);
        float4 e0 = ep[0], e1 = ep[1], e2 = ep[2], e3 = ep[3];
        eavl[0]=e0.x*inv; eavl[1]=e0.y*inv; eavl[2]=e0.z*inv; eavl[3]=e0.w*inv;
        eavl[4]=e1.x*inv; eavl[5]=e1.y*inv; eavl[6]=e1.z*inv; eavl[7]=e1.w*inv;
        eavl[8]=e2.x*inv; eavl[9]=e2.y*inv; eavl[10]=e2.z*inv; eavl[11]=e2.w*inv;
        eavl[12]=e3.x*inv; eavl[13]=e3.y*inv; eavl[14]=e3.z*inv; eavl[15]=e3.w*inv;
    }
    float al_loop = edge_score(eavl, pld, xr0, xr1, w0, w1, a0, a1);
    float m_run = al_loop, l_run = 1.0f;
    float n0 = bfl(pld), n1 = bfh(pld);
    int i = beg;
    // prefetch first group's source indices (SGPRs after readfirstlane)
    int sA = 0, sB = 0, sC = 0, sD = 0;
    if (i + 3 < end) {
        sA = rfl(csr_src[i]);     sB = rfl(csr_src[i + 1]);
        sC = rfl(csr_src[i + 2]); sD = rfl(csr_src[i + 3]);
    }
    for (; i + 3 < end; ) {
        int s0 = sA, s1 = sB, s2 = sC, s3 = sD;
        // issue xl gathers first (longest-latency chain)
        unsigned p0 = xlw[(size_t)s0 * 64 + lane];
        unsigned p1 = xlw[(size_t)s1 * 64 + lane];
        unsigned p2 = xlw[(size_t)s2 * 64 + lane];
        unsigned p3 = xlw[(size_t)s3 * 64 + lane];
        // prefetch next group's indices (clamped: harmless re-read)
        int inext = i + 4;
        int ipre = (inext + 3 < end) ? inext : i;
        sA = rfl(csr_src[ipre]);     sB = rfl(csr_src[ipre + 1]);
        sC = rfl(csr_src[ipre + 2]); sD = rfl(csr_src[ipre + 3]);
        // sequential ea loads
        uint4 qa0 = eap[(size_t)i * 2],       qa1 = eap[(size_t)i * 2 + 1];
        uint4 qb0 = eap[(size_t)(i + 1) * 2], qb1 = eap[(size_t)(i + 1) * 2 + 1];
        uint4 qc0 = eap[(size_t)(i + 2) * 2], qc1 = eap[(size_t)(i + 2) * 2 + 1];
        uint4 qd0 = eap[(size_t)(i + 3) * 2], qd1 = eap[(size_t)(i + 3) * 2 + 1];
        float ea0[16], ea1[16], ea2[16], ea3[16];
        unp16(qa0, qa1, ea0); unp16(qb0, qb1, ea1);
        unp16(qc0, qc1, ea2); unp16(qd0, qd1, ea3);
        float al0 = edge_score(ea0, p0, xr0, xr1, w0, w1, a0, a1);
        float al1 = edge_score(ea1, p1, xr0, xr1, w0, w1, a0, a1);
        float al2 = edge_score(ea2, p2, xr0, xr1, w0, w1, a0, a1);
        float al3 = edge_score(ea3, p3, xr0, xr1, w0, w1, a0, a1);
        online_upd(al0, p0, m_run, l_run, n0, n1);
        online_upd(al1, p1, m_run, l_run, n0, n1);
        online_upd(al2, p2, m_run, l_run, n0, n1);
        online_upd(al3, p3, m_run, l_run, n0, n1);
        i = inext;
    }
    for (; i < end; ++i) {
        int s = rfl(csr_src[i]);
        uint4 q0 = eap[(size_t)i * 2], q1 = eap[(size_t)i * 2 + 1];
        unsigned p = xlw[(size_t)s * 64 + lane];
        float ea[16];
        unp16(q0, q1, ea);
        float al = edge_score(ea, p, xr0, xr1, w0, w1, a0, a1);
        online_upd(al, p, m_run, l_run, n0, n1);
    }
    float rinv = 1.0f / l_run;
    float2 bv = *(const float2*)(bias2 + 2 * lane);
    float o0 = n0 * rinv + bv.x;
    float o1 = n1 * rinv + bv.y;
    int g = batch[d];
    atomAddF(&gsum[(size_t)g * 128 + 2 * lane], o0);
    atomAddF(&gsum[(size_t)g * 128 + 2 * lane + 1], o1);
    if (lane == 0) atomAddF(&cnt[g], 1.0f);
}

// ---------------- Kernel G: FFN ----------------------------------------------
__global__ __launch_bounds__(256) void k_ffn(
    const float* __restrict__ gsum, const float* __restrict__ cnt,
    const float* __restrict__ W1, const float* __restrict__ b1,
    const float* __restrict__ W2, const float* __restrict__ b2,
    float* __restrict__ y) {
    __shared__ float row[128];
    __shared__ float red[4];
    int g = blockIdx.x;
    int t = threadIdx.x;
    if (t < 128) row[t] = gsum[(size_t)g * 128 + t] / fmaxf(cnt[g], 1.0f);
    __syncthreads();
    float part = 0.f;
    #pragma unroll
    for (int jj = 0; jj < 2; ++jj) {
        int j = t + jj * 256;
        float acc = b1[j];
        for (int k = 0; k < 128; ++k) acc += row[k] * W1[k * 512 + j];
        part += gelu_t(acc) * W2[j];
    }
    #pragma unroll
    for (int off = 32; off; off >>= 1) part += __shfl_xor(part, off, 64);
    if ((t & 63) == 0) red[t >> 6] = part;
    __syncthreads();
    if (t == 0) y[g] = red[0] + red[1] + red[2] + red[3] + b2[0];
}

extern "C" void kernel_launch(void* const* d_in, const int* in_sizes, int n_in,
                              void* d_out, int out_size, void* d_ws, size_t ws_size,
                              hipStream_t stream) {
    const float* x      = (const float*)d_in[0];
    const int*   eidx   = (const int*)d_in[1];
    const float* eattr  = (const float*)d_in[2];
    const int*   batch  = (const int*)d_in[3];
    const float* W_msg  = (const float*)d_in[4];
    const float* b_msg  = (const float*)d_in[5];
    const float* W_e1   = (const float*)d_in[6];
    const float* b_e1   = (const float*)d_in[7];
    const float* W_self = (const float*)d_in[8];
    const float* b_self = (const float*)d_in[9];
    const float* W_l    = (const float*)d_in[10];
    const float* b_l    = (const float*)d_in[11];
    const float* W_r    = (const float*)d_in[12];
    const float* b_r    = (const float*)d_in[13];
    const float* W_e2   = (const float*)d_in[14];
    const float* att    = (const float*)d_in[15];
    const float* bias2  = (const float*)d_in[16];
    const float* W1     = (const float*)d_in[17];
    const float* b1     = (const float*)d_in[18];
    const float* W2     = (const float*)d_in[19];
    const float* b2     = (const float*)d_in[20];
    const int* src = eidx;
    const int* dst = eidx + NE;

    char* wsb = (char*)d_ws;
    size_t o = 0;
    // --- zero region: hist, gsum, cnt ---
    int*   hist   = (int*)(wsb + o);   o += (size_t)NN * 4;
    float* gsum   = (float*)(wsb + o); o += (size_t)NG * 128 * 4;
    float* cnt    = (float*)(wsb + o); o += 4096;
    size_t zero_bytes = o;
    // --- rest (16B-aligned chunks) ---
    int*   row_ptr = (int*)(wsb + o);  o += (size_t)(NN + 4) * 4;
    int*   cursor  = (int*)(wsb + o);  o += (size_t)NN * 4;
    int*   csr_src = (int*)(wsb + o);  o += (size_t)NE * 4;
    unsigned short* ea_csr = (unsigned short*)(wsb + o); o += (size_t)NE * 16 * 2;
    unsigned short* aggx_bf  = (unsigned short*)(wsb + o); o += (size_t)NN * 64 * 2;
    float* agg_ea  = (float*)(wsb + o); o += (size_t)NN * 16 * 4;
    unsigned short* aggea_bf = (unsigned short*)(wsb + o); o += (size_t)NN * 16 * 2;
    float* degf    = (float*)(wsb + o); o += (size_t)NN * 4;
    unsigned short* x_bf  = (unsigned short*)(wsb + o); o += (size_t)NN * 64 * 2;
    unsigned short* xl_bf = (unsigned short*)(wsb + o); o += (size_t)NN * 128 * 2;
    unsigned short* xr_bf = (unsigned short*)(wsb + o); o += (size_t)NN * 128 * 2;
    unsigned short* wf1   = (unsigned short*)(wsb + o); o += (size_t)5120 * 8 * 2;
    unsigned short* wf2   = (unsigned short*)(wsb + o); o += (size_t)8192 * 8 * 2;
    float* bsum2  = (float*)(wsb + o); o += 1024;

    hipMemsetAsync(d_ws, 0, zero_bytes, stream);
    hipLaunchKernelGGL(k_pre, dim3(2500), dim3(256), 0, stream,
                       x, dst, W_self, W_msg, W_e1, b_msg, b_e1, W_l, W_r,
                       x_bf, hist, wf1, wf2, bsum2);
    hipLaunchKernelGGL(k_scan, dim3(1), dim3(1024), 0, stream, hist, row_ptr, cursor);
    hipLaunchKernelGGL(k_scatter, dim3(2500), dim3(256), 0, stream,
                       src, dst, eattr, cursor, csr_src, ea_csr);
    hipLaunchKernelGGL(k_agg, dim3((NN + 3) / 4), dim3(256), 0, stream,
                       x_bf, ea_csr, csr_src, row_ptr, aggx_bf, agg_ea, aggea_bf, degf);
    hipLaunchKernelGGL(k_hx, dim3(625), dim3(256), 0, stream,
                       x_bf, aggx_bf, aggea_bf, degf, wf1, wf2,
                       b_self, bsum2, b_l, b_r, xl_bf, xr_bf);
    hipLaunchKernelGGL(k_gat, dim3((NN + 3) / 4), dim3(256), 0, stream,
                       (const unsigned*)xl_bf, (const unsigned*)xr_bf, ea_csr,
                       csr_src, row_ptr, agg_ea, W_e2, att, bias2,
                       batch, gsum, cnt);
    hipLaunchKernelGGL(k_ffn, dim3(NG), dim3(256), 0, stream,
                       gsum, cnt, W1, b1, W2, b2, (float*)d_out);
}